// Round 11
// baseline (176.172 us; speedup 1.0000x reference)
//
#include <hip/hip_runtime.h>
#include <math.h>

#define B_ 4
#define N_ 2048
#define M_ 4096

#define ADDS_BLOCKS (B_ * (N_ / 8))      // 1024
#define RANK_BLOCKS (B_ * (N_ / 16))     // 512

// ---- constants (fp32 copies of the reference's) ----
__constant__ float c_LO[10] = {0.0f, 0.00794435329f, 0.0158887021f, 0.0238330509f,
                               0.0317773996f, 0.0397217484f, 0.0476660972f,
                               0.0556104459f, 0.0635547947f, 0.0714991435f};
__constant__ float c_HI[10] = {0.00794435329f, 0.0158887021f, 0.0238330509f,
                               0.0317773996f, 0.0397217484f, 0.0476660972f,
                               0.0556104459f, 0.0635547947f, 0.0714991435f, 0.08f};
__constant__ float c_BW[10] = {0.16652107f, 0.21488856f, 0.37031708f, 0.55618503f,
                               0.75124664f, 0.93943357f, 1.07824539f, 1.19423112f,
                               1.55731375f, 2.34173634f};

#define R2_ 2.5e-05f   // fp32(0.005**2) — matches JAX weak-type cast
#define FAR_ 100000.0f
#define EPS_ 1e-07f

// ---------------------------------------------------------------------------
// JAX threefry2x32, key = jax.random.key(42) -> (0, 42)
__device__ inline unsigned rotl32(unsigned x, int d) { return (x << d) | (x >> (32 - d)); }

__device__ inline void threefry2x32_42(unsigned x0, unsigned x1, unsigned& o0, unsigned& o1) {
    const unsigned k0 = 0u, k1 = 42u;
    const unsigned k2 = k0 ^ k1 ^ 0x1BD11BDAu;
    const unsigned ks[3] = {k0, k1, k2};
    const int rot[2][4] = {{13, 15, 26, 6}, {17, 29, 16, 24}};
    unsigned v0 = x0 + k0;
    unsigned v1 = x1 + k1;
#pragma unroll
    for (int i = 0; i < 5; ++i) {
        const int* r = rot[i & 1];
#pragma unroll
        for (int j = 0; j < 4; ++j) {
            v0 += v1;
            v1 = rotl32(v1, r[j]);
            v1 ^= v0;
        }
        v0 += ks[(i + 1) % 3];
        v1 += ks[(i + 2) % 3] + (unsigned)(i + 1);
    }
    o0 = v0; o1 = v1;
}

__device__ inline float bits_to_uniform(unsigned bits) {
    float f = __uint_as_float((bits >> 9) | 0x3f800000u) - 1.0f;
    return fmaxf(0.0f, f);
}

__device__ inline float jax_uniform_r(int flat) {
    unsigned o0, o1;
    if (flat < 4096) {
        threefry2x32_42((unsigned)flat, (unsigned)(flat + 4096), o0, o1);
        return bits_to_uniform(o0);
    } else {
        threefry2x32_42((unsigned)(flat - 4096), (unsigned)flat, o0, o1);
        return bits_to_uniform(o1);
    }
}

// ---------------------------------------------------------------------------
// K0: pack contact points -> float4 {x,y,z,|q|^2}; zero counters.
__global__ __launch_bounds__(256) void pack_contacts(const float* __restrict__ pts,
                                                     float4* __restrict__ out,
                                                     int* __restrict__ counters) {
    int i = blockIdx.x * blockDim.x + threadIdx.x;
    if (i == 0) { counters[0] = 0; counters[1] = 0; }
    if (i >= B_ * M_) return;
    float x = pts[(size_t)i * 3 + 0];
    float y = pts[(size_t)i * 3 + 1];
    float z = pts[(size_t)i * 3 + 2];
    out[i] = make_float4(x, y, z, x * x + y * y + z * z);
}

// ---------------------------------------------------------------------------
// K1: fused NN + prep. Grid = B*(N/8) = 1024 blocks.
// part p owns j = jj*128 + p (coalesced cpack reads: lane pairs share an
// address, 32 consecutive float4s per load instruction).
// G written in quad-SoA: comp c of (b,n) at Gt[((b*8+c/4)*N_+n)*4 + (c%4)].
__global__ __launch_bounds__(256, 4) void nn_prep_kernel(
        const float* __restrict__ ppts, const float4* __restrict__ cpack,
        const float* __restrict__ pred_grasps,
        const float* __restrict__ rot, const float* __restrict__ trans,
        const float* __restrict__ cp, const float* __restrict__ cps,
        int* __restrict__ idx_out, float* __restrict__ d2_out,
        float* __restrict__ Pout, float* __restrict__ Gt) {
    int blk = blockIdx.x;
    int b = blk / (N_ / 8);
    int tile = blk % (N_ / 8);
    int tid = threadIdx.x;
    int ig = tid & 1;             // i-group: 4 consecutive i's
    int part = tid >> 1;          // 0..127
    int i0 = tile * 8 + ig * 4;

    float ax[4], ay[4], az[4], an[4];
#pragma unroll
    for (int ii = 0; ii < 4; ++ii) {
        const float* pp = ppts + ((size_t)b * N_ + i0 + ii) * 3;
        ax[ii] = pp[0]; ay[ii] = pp[1]; az[ii] = pp[2];
        an[ii] = ax[ii] * ax[ii] + ay[ii] * ay[ii] + az[ii] * az[ii];
    }

    const float4* cb = cpack + (size_t)b * M_;
    float best[4] = {INFINITY, INFINITY, INFINITY, INFINITY};
    int bidx[4] = {0, 0, 0, 0};
    for (int jj = 0; jj < 32; jj += 4) {
        float4 q4[4];
#pragma unroll
        for (int k = 0; k < 4; ++k) q4[k] = cb[(jj + k) * 128 + part];
#pragma unroll
        for (int k = 0; k < 4; ++k) {
            int j = (jj + k) * 128 + part;   // ascending within thread
#pragma unroll
            for (int ii = 0; ii < 4; ++ii) {
                float cross = ax[ii] * q4[k].x + ay[ii] * q4[k].y + az[ii] * q4[k].z;
                float d = an[ii] + q4[k].w - 2.0f * cross;
                d = fmaxf(d, 0.0f);
                if (d < best[ii]) { best[ii] = d; bidx[ii] = j; }  // first occurrence
            }
        }
    }

    __shared__ float sd[8][128];
    __shared__ int si[8][128];
#pragma unroll
    for (int ii = 0; ii < 4; ++ii) {
        sd[ig * 4 + ii][part] = best[ii];
        si[ig * 4 + ii][part] = bidx[ii];
    }
    __syncthreads();

    if (tid < 8) {
        int n = tile * 8 + tid;
        float bb = INFINITY;
        int bi = 0x7fffffff;
        for (int p = 0; p < 128; ++p) {
            float dv = sd[tid][p];
            int iv = si[tid][p];
            // explicit tie-break on smallest j (interleaved part sets)
            if (dv < bb || (dv == bb && iv < bi)) { bb = dv; bi = iv; }
        }
        idx_out[b * N_ + n] = bi;
        d2_out[b * N_ + n] = bb;

        // ---- inline prep for this n ----
        size_t i = (size_t)b * N_ + n;
        const float* g = pred_grasps + i * 16;
        float R[3][3] = {{g[0], g[1], g[2]}, {g[4], g[5], g[6]}, {g[8], g[9], g[10]}};
        float t[3] = {g[3], g[7], g[11]};

        float* P = Pout + i * 16;
        float pn = 0.0f;
#pragma unroll
        for (int c = 0; c < 5; ++c) {
            float cx = cp[c * 3], cy = cp[c * 3 + 1], cz = cp[c * 3 + 2];
#pragma unroll
            for (int kk = 0; kk < 3; ++kk) {
                float v = R[kk][0] * cx + R[kk][1] * cy + R[kk][2] * cz + t[kk];
                P[c * 3 + kk] = v;
                pn += v * v;
            }
        }
        P[15] = pn;

        bool succ = bb < R2_;
        float RL[3][3], TL[3];
        if (succ) {
            const float* rl = rot + ((size_t)b * M_ + bi) * 9;
#pragma unroll
            for (int a = 0; a < 3; ++a)
#pragma unroll
                for (int c2 = 0; c2 < 3; ++c2) RL[a][c2] = rl[a * 3 + c2];
            const float* tl = trans + ((size_t)b * M_ + bi) * 3;
            TL[0] = tl[0]; TL[1] = tl[1]; TL[2] = tl[2];
        } else {
#pragma unroll
            for (int a = 0; a < 3; ++a) {
#pragma unroll
                for (int c2 = 0; c2 < 3; ++c2) RL[a][c2] = FAR_;
                TL[a] = FAR_;
            }
        }

        // quad-SoA G write: comp c -> gtb[(c/4)*N_*4 + (c%4)]
        float* gtb = Gt + ((size_t)b * 8 * N_ + n) * 4;
        float gn = 0.0f, gsn = 0.0f;
#pragma unroll
        for (int c = 0; c < 5; ++c) {
            float cx = cp[c * 3], cy = cp[c * 3 + 1], cz = cp[c * 3 + 2];
#pragma unroll
            for (int kk = 0; kk < 3; ++kk) {
                int comp = c * 3 + kk;
                float v = RL[kk][0] * cx + RL[kk][1] * cy + RL[kk][2] * cz + TL[kk];
                gtb[(size_t)(comp >> 2) * (N_ * 4) + (comp & 3)] = v;
                gn += v * v;
            }
        }
        gtb[(size_t)(15 >> 2) * (N_ * 4) + (15 & 3)] = gn;
#pragma unroll
        for (int c = 0; c < 5; ++c) {
            float cx = cps[c * 3], cy = cps[c * 3 + 1], cz = cps[c * 3 + 2];
#pragma unroll
            for (int kk = 0; kk < 3; ++kk) {
                int comp = 16 + c * 3 + kk;
                float v = RL[kk][0] * cx + RL[kk][1] * cy + RL[kk][2] * cz + TL[kk];
                gtb[(size_t)(comp >> 2) * (N_ * 4) + (comp & 3)] = v;
                gsn += v * v;
            }
        }
        gtb[(size_t)(31 >> 2) * (N_ * 4) + (31 & 3)] = gsn;
    }
}

// ---------------------------------------------------------------------------
// K2: merged adds + rank (both depend only on K1; block-role split).
//   [0, 1024):  ADD-S min with quad-SoA G (R10-measured winner)
//   [1024, 1536): hard-negative selection (R6-measured structure)
__global__ __launch_bounds__(256, 4) void work_kernel(
        const float* __restrict__ Parr, const float4* __restrict__ Gt4,
        float* __restrict__ mOut,
        const float* __restrict__ d2w, float* __restrict__ selws) {
    __shared__ __align__(16) char smem[9600];
    int bid = blockIdx.x;
    int tid = threadIdx.x;

    if (bid < ADDS_BLOCKS) {
        // ================= adds role =================
        int b = bid >> 8;                  // 256 blocks per batch
        int tile = bid & 255;
        int w = tid >> 6;                  // wave 0..3
        int lane = tid & 63;
        int i0 = tile * 8 + w * 2;

        const float4* P4 = reinterpret_cast<const float4*>(Parr) +
                           ((size_t)b * N_ + i0) * 4;
        float Pv[2][16];
#pragma unroll
        for (int h = 0; h < 2; ++h)
#pragma unroll
            for (int q = 0; q < 4; ++q) {
                float4 v = P4[h * 4 + q];
                Pv[h][q * 4 + 0] = v.x; Pv[h][q * 4 + 1] = v.y;
                Pv[h][q * 4 + 2] = v.z; Pv[h][q * 4 + 3] = v.w;
            }

        const float4* gq = Gt4 + (size_t)b * 8 * N_;
        float best0 = INFINITY, best1 = INFINITY;
        for (int jb = 0; jb < N_ / 64; ++jb) {
            int j = jb * 64 + lane;
            float g[16];
            // half 1: quads 0..3 = comps 0..15 (G + norm)
            {
                float4 h0 = gq[(size_t)0 * N_ + j];
                float4 h1 = gq[(size_t)1 * N_ + j];
                float4 h2 = gq[(size_t)2 * N_ + j];
                float4 h3 = gq[(size_t)3 * N_ + j];
                g[0] = h0.x; g[1] = h0.y; g[2] = h0.z; g[3] = h0.w;
                g[4] = h1.x; g[5] = h1.y; g[6] = h1.z; g[7] = h1.w;
                g[8] = h2.x; g[9] = h2.y; g[10] = h2.z; g[11] = h2.w;
                g[12] = h3.x; g[13] = h3.y; g[14] = h3.z; g[15] = h3.w;
            }
            float d00 = 0.0f, d10 = 0.0f;
#pragma unroll
            for (int q = 0; q < 15; ++q) {
                d00 += Pv[0][q] * g[q];
                d10 += Pv[1][q] * g[q];
            }
            float s00 = Pv[0][15] + g[15] - 2.0f * d00;
            float s10 = Pv[1][15] + g[15] - 2.0f * d10;
            // half 2: quads 4..7 = comps 16..31 (Gs + norm)
            {
                float4 h0 = gq[(size_t)4 * N_ + j];
                float4 h1 = gq[(size_t)5 * N_ + j];
                float4 h2 = gq[(size_t)6 * N_ + j];
                float4 h3 = gq[(size_t)7 * N_ + j];
                g[0] = h0.x; g[1] = h0.y; g[2] = h0.z; g[3] = h0.w;
                g[4] = h1.x; g[5] = h1.y; g[6] = h1.z; g[7] = h1.w;
                g[8] = h2.x; g[9] = h2.y; g[10] = h2.z; g[11] = h2.w;
                g[12] = h3.x; g[13] = h3.y; g[14] = h3.z; g[15] = h3.w;
            }
            float d01 = 0.0f, d11 = 0.0f;
#pragma unroll
            for (int q = 0; q < 15; ++q) {
                d01 += Pv[0][q] * g[q];
                d11 += Pv[1][q] * g[q];
            }
            float s01 = Pv[0][15] + g[15] - 2.0f * d01;
            float s11 = Pv[1][15] + g[15] - 2.0f * d11;
            best0 = fminf(best0, fminf(s00, s01));
            best1 = fminf(best1, fminf(s10, s11));
        }
        // 64-lane min butterfly
#pragma unroll
        for (int m = 32; m > 0; m >>= 1) {
            best0 = fminf(best0, __shfl_xor(best0, m));
            best1 = fminf(best1, __shfl_xor(best1, m));
        }
        if (lane == 0) {
            mOut[b * N_ + i0 + 0] = best0;
            mOut[b * N_ + i0 + 1] = best1;
        }
    } else {
        // ================= rank role =================
        int rid = bid - ADDS_BLOCKS;
        int b = rid / (N_ / 16);
        int tile = rid % (N_ / 16);
        int n_local = tid & 15;
        int part = tid >> 4;               // 0..15

        float* pri = (float*)smem;                   // [2048] floats
        int* cnt_sh = (int*)(smem + 8192);           // [16][17]
        __shared__ int s_npos;
        if (tid == 0) s_npos = 0;
        __syncthreads();

        int lp = 0;
        for (int q = tid; q < N_; q += 256) {
            bool pos = d2w[b * N_ + q] < R2_;
            pri[q] = pos ? INFINITY : jax_uniform_r(b * N_ + q);
            if (pos) lp++;
        }
        atomicAdd(&s_npos, lp);
        __syncthreads();

        int n = tile * 16 + n_local;
        float ra = pri[n];

        int cnt = 0;
        const float4* p4 = reinterpret_cast<const float4*>(pri);
        for (int o = 0; o < 8; ++o) {
            float4 v[4];
#pragma unroll
            for (int k = 0; k < 4; ++k) v[k] = p4[part + (o * 4 + k) * 16];
#pragma unroll
            for (int k = 0; k < 4; ++k) {
                int qb = (part + (o * 4 + k) * 16) * 4;
                cnt += ((v[k].x < ra) || (v[k].x == ra && (qb + 0) < n)) ? 1 : 0;
                cnt += ((v[k].y < ra) || (v[k].y == ra && (qb + 1) < n)) ? 1 : 0;
                cnt += ((v[k].z < ra) || (v[k].z == ra && (qb + 2) < n)) ? 1 : 0;
                cnt += ((v[k].w < ra) || (v[k].w == ra && (qb + 3) < n)) ? 1 : 0;
            }
        }
        cnt_sh[part * 17 + n_local] = cnt;
        __syncthreads();

        if (tid < 16) {
            int tot = 0;
#pragma unroll
            for (int p = 0; p < 16; ++p) tot += cnt_sh[p * 17 + tid];
            int npos = s_npos;
            int kk = (npos > 0) ? npos : 2;
            int n2 = tile * 16 + tid;
            float r2 = pri[n2];
            selws[b * N_ + n2] = (r2 == INFINITY) ? 1.0f : ((tot < kk) ? 1.0f : 0.0f);
        }
    }
}

// ---------------------------------------------------------------------------
// K3: per-batch sums (R6-measured structure). Grid = B*8 = 32 blocks,
// 1 n per thread. Fixed-order partials + last-block deterministic combine.
__global__ __launch_bounds__(256) void finalize_kernel(
        const float* __restrict__ scores, const float* __restrict__ gwh,
        const float* __restrict__ pcw, const int* __restrict__ idxw,
        const float* __restrict__ d2w, const float* __restrict__ mw,
        const float* __restrict__ selws,
        float* __restrict__ partials, int* __restrict__ counters,
        float* __restrict__ out) {
    int fid = blockIdx.x;                  // 0..31
    int b = fid >> 3;
    int part = fid & 7;
    int tid = threadIdx.x;
    int n = part * 256 + tid;
    __shared__ float wsum[4][5];

    float sc = scores[b * N_ + n];
    float pcl = fminf(fmaxf(sc, EPS_), 0.9999999f);
    bool pos = d2w[b * N_ + n] < R2_;
    float s = pos ? 1.0f : 0.0f;
    float bce = -(s * logf(pcl) + (1.0f - s) * logf(1.0f - pcl));
    float selv = selws[b * N_ + n];
    float sum_sel = selv;
    float sum_bce = bce * selv;
    float sum_pos = s;
    float sum_wl = 0.0f, sum_adds = 0.0f;
    if (pos) {
        int jx = idxw[b * N_ + n];
        float w = pcw[b * M_ + jx];
        float acc = 0.0f;
#pragma unroll
        for (int jb = 0; jb < 10; ++jb) {
            float x = gwh[((size_t)b * 10 + jb) * N_ + n];
            float mh = (w >= c_LO[jb] && w < c_HI[jb]) ? 1.0f : 0.0f;
            float bw = fmaxf(x, 0.0f) - x * mh + log1pf(expf(-fabsf(x)));
            acc += c_BW[jb] * bw;
        }
        sum_wl = acc * 0.1f;
        float mv = mw[b * N_ + n];
        sum_adds = sc * sqrtf(fmaxf(mv, 0.0f) + 1e-12f);
    }

    // deterministic reduce: wave shuffle + per-wave LDS + thread-0 combine
    float v0 = sum_sel, v1 = sum_bce, v2 = sum_wl, v3 = sum_adds, v4 = sum_pos;
#pragma unroll
    for (int off = 32; off > 0; off >>= 1) {
        v0 += __shfl_down(v0, off);
        v1 += __shfl_down(v1, off);
        v2 += __shfl_down(v2, off);
        v3 += __shfl_down(v3, off);
        v4 += __shfl_down(v4, off);
    }
    int wv = tid >> 6, lane = tid & 63;
    if (lane == 0) {
        wsum[wv][0] = v0; wsum[wv][1] = v1; wsum[wv][2] = v2;
        wsum[wv][3] = v3; wsum[wv][4] = v4;
    }
    __syncthreads();
    if (tid == 0) {
        float t0 = 0, t1 = 0, t2 = 0, t3 = 0, t4 = 0;
#pragma unroll
        for (int w = 0; w < 4; ++w) {
            t0 += wsum[w][0]; t1 += wsum[w][1]; t2 += wsum[w][2];
            t3 += wsum[w][3]; t4 += wsum[w][4];
        }
        float* pp = partials + (size_t)fid * 5;
        pp[0] = t0; pp[1] = t1; pp[2] = t2; pp[3] = t3; pp[4] = t4;
        __threadfence();
        int old = atomicAdd(&counters[1], 1);
        if (old == 32 - 1) {
            __threadfence();
            float bin = 0, wid = 0, ad = 0;
#pragma unroll
            for (int b2 = 0; b2 < B_; ++b2) {
                float u0 = 0, u1 = 0, u2 = 0, u3 = 0, u4 = 0;
#pragma unroll
                for (int p2 = 0; p2 < 8; ++p2) {       // fixed order: deterministic
                    const float* q = partials + (size_t)(b2 * 8 + p2) * 5;
                    u0 += q[0]; u1 += q[1]; u2 += q[2]; u3 += q[3]; u4 += q[4];
                }
                float piv = fmaxf(u4, 1.0f);           // pos_in_view
                bin += u1 / fmaxf(u0, 1.0f);
                wid += u2 / piv;
                ad  += u3 / piv;
            }
            bin *= 0.25f; wid *= 0.25f; ad *= 0.25f;
            out[0] = bin + wid + 3.0f * ad;
            out[1] = bin;
            out[2] = wid;
            out[3] = ad;
        }
    }
}

// ---------------------------------------------------------------------------
extern "C" void kernel_launch(void* const* d_in, const int* in_sizes, int n_in,
                              void* d_out, int out_size, void* d_ws, size_t ws_size,
                              hipStream_t stream) {
    const float* pred_grasps = (const float*)d_in[0];   // (4,2048,4,4)
    const float* pred_scores = (const float*)d_in[1];   // (4,2048,1)
    const float* pred_points = (const float*)d_in[2];   // (4,2048,3)
    const float* gwh         = (const float*)d_in[3];   // (4,10,2048)
    const float* pcp         = (const float*)d_in[4];   // (4,4096,3)
    const float* pcw         = (const float*)d_in[5];   // (4,4096)
    const float* pcr         = (const float*)d_in[6];   // (4,4096,3,3)
    const float* pct         = (const float*)d_in[7];   // (4,4096,3)
    const float* cp          = (const float*)d_in[8];   // (1,5,3)
    const float* cps         = (const float*)d_in[9];   // (1,5,3)
    (void)in_sizes; (void)n_in; (void)out_size; (void)ws_size;

    float* ws = (float*)d_ws;
    float4* cpack = (float4*)ws;                        //  65536 floats
    int*   idxw  = (int*)(ws + 65536);                  //   8192
    float* d2w   = ws + 65536 + 8192;                   //   8192
    float* Pw    = ws + 65536 + 16384;                  // 131072
    float* Gt    = Pw + 131072;                         // 262144 (quad-SoA)
    float* mw    = Gt + 262144;                         //   8192
    float* selws = mw + 8192;                           //   8192
    float* parts = selws + 8192;                        //    160
    int*   ctrs  = (int*)(parts + 160);                 //      2
    float* outp  = (float*)d_out;

    hipLaunchKernelGGL(pack_contacts, dim3((B_ * M_ + 255) / 256), dim3(256), 0, stream,
                       pcp, cpack, ctrs);
    hipLaunchKernelGGL(nn_prep_kernel, dim3(B_ * (N_ / 8)), dim3(256), 0, stream,
                       pred_points, cpack, pred_grasps, pcr, pct, cp, cps,
                       idxw, d2w, Pw, Gt);
    hipLaunchKernelGGL(work_kernel, dim3(ADDS_BLOCKS + RANK_BLOCKS), dim3(256), 0, stream,
                       Pw, (const float4*)Gt, mw, d2w, selws);
    hipLaunchKernelGGL(finalize_kernel, dim3(B_ * 8), dim3(256), 0, stream,
                       pred_scores, gwh, pcw, idxw, d2w, mw, selws, parts, ctrs, outp);
}

// Round 12
// 161.518 us; speedup vs baseline: 1.0907x; 1.0907x over previous
//
#include <hip/hip_runtime.h>
#include <math.h>

#define B_ 4
#define N_ 2048
#define M_ 4096

// ---- constants (fp32 copies of the reference's) ----
__constant__ float c_LO[10] = {0.0f, 0.00794435329f, 0.0158887021f, 0.0238330509f,
                               0.0317773996f, 0.0397217484f, 0.0476660972f,
                               0.0556104459f, 0.0635547947f, 0.0714991435f};
__constant__ float c_HI[10] = {0.00794435329f, 0.0158887021f, 0.0238330509f,
                               0.0317773996f, 0.0397217484f, 0.0476660972f,
                               0.0556104459f, 0.0635547947f, 0.0714991435f, 0.08f};
__constant__ float c_BW[10] = {0.16652107f, 0.21488856f, 0.37031708f, 0.55618503f,
                               0.75124664f, 0.93943357f, 1.07824539f, 1.19423112f,
                               1.55731375f, 2.34173634f};

#define R2_ 2.5e-05f   // fp32(0.005**2) — matches JAX weak-type cast
#define FAR_ 100000.0f
#define EPS_ 1e-07f

// ---------------------------------------------------------------------------
// JAX threefry2x32, key = jax.random.key(42) -> (0, 42)
__device__ inline unsigned rotl32(unsigned x, int d) { return (x << d) | (x >> (32 - d)); }

__device__ inline void threefry2x32_42(unsigned x0, unsigned x1, unsigned& o0, unsigned& o1) {
    const unsigned k0 = 0u, k1 = 42u;
    const unsigned k2 = k0 ^ k1 ^ 0x1BD11BDAu;
    const unsigned ks[3] = {k0, k1, k2};
    const int rot[2][4] = {{13, 15, 26, 6}, {17, 29, 16, 24}};
    unsigned v0 = x0 + k0;
    unsigned v1 = x1 + k1;
#pragma unroll
    for (int i = 0; i < 5; ++i) {
        const int* r = rot[i & 1];
#pragma unroll
        for (int j = 0; j < 4; ++j) {
            v0 += v1;
            v1 = rotl32(v1, r[j]);
            v1 ^= v0;
        }
        v0 += ks[(i + 1) % 3];
        v1 += ks[(i + 2) % 3] + (unsigned)(i + 1);
    }
    o0 = v0; o1 = v1;
}

__device__ inline float bits_to_uniform(unsigned bits) {
    float f = __uint_as_float((bits >> 9) | 0x3f800000u) - 1.0f;
    return fmaxf(0.0f, f);
}

__device__ inline float jax_uniform_r(int flat) {
    unsigned o0, o1;
    if (flat < 4096) {
        threefry2x32_42((unsigned)flat, (unsigned)(flat + 4096), o0, o1);
        return bits_to_uniform(o0);
    } else {
        threefry2x32_42((unsigned)(flat - 4096), (unsigned)flat, o0, o1);
        return bits_to_uniform(o1);
    }
}

// ---------------------------------------------------------------------------
// K1: fused NN + prep (R10-measured structure: pcp read directly from d_in).
// Grid = B*(N/8) = 1024 blocks.
// G written in quad-SoA: comp c of (b,n) at Gt[((b*8+c/4)*N_+n)*4 + (c%4)].
__global__ __launch_bounds__(256, 4) void nn_prep_kernel(
        const float* __restrict__ ppts, const float* __restrict__ pcp,
        const float* __restrict__ pred_grasps,
        const float* __restrict__ rot, const float* __restrict__ trans,
        const float* __restrict__ cp, const float* __restrict__ cps,
        int* __restrict__ idx_out, float* __restrict__ d2_out,
        float* __restrict__ Pout, float* __restrict__ Gt,
        int* __restrict__ counters) {
    if (blockIdx.x == 0 && threadIdx.x == 0) { counters[0] = 0; counters[1] = 0; }
    int blk = blockIdx.x;
    int b = blk / (N_ / 8);
    int tile = blk % (N_ / 8);
    int tid = threadIdx.x;
    int ig = tid & 1;             // i-group: 4 consecutive i's
    int part = tid >> 1;          // 0..127
    int i0 = tile * 8 + ig * 4;

    float ax[4], ay[4], az[4], an[4];
#pragma unroll
    for (int ii = 0; ii < 4; ++ii) {
        const float* pp = ppts + ((size_t)b * N_ + i0 + ii) * 3;
        ax[ii] = pp[0]; ay[ii] = pp[1]; az[ii] = pp[2];
        an[ii] = ax[ii] * ax[ii] + ay[ii] * ay[ii] + az[ii] * az[ii];
    }

    const float4* pb4 = reinterpret_cast<const float4*>(pcp + (size_t)b * M_ * 3);
    float best[4] = {INFINITY, INFINITY, INFINITY, INFINITY};
    int bidx[4] = {0, 0, 0, 0};
    for (int g = 0; g < 8; ++g) {
        int grp = g * 128 + part;            // group of 4 contact points
        float4 q0 = pb4[grp * 3 + 0];
        float4 q1 = pb4[grp * 3 + 1];
        float4 q2 = pb4[grp * 3 + 2];
        float px[4] = {q0.x, q0.w, q1.z, q2.y};
        float py[4] = {q0.y, q1.x, q1.w, q2.z};
        float pz[4] = {q0.z, q1.y, q2.x, q2.w};
#pragma unroll
        for (int k = 0; k < 4; ++k) {
            float bn = px[k] * px[k] + py[k] * py[k] + pz[k] * pz[k];
            int j = grp * 4 + k;             // ascending within thread
#pragma unroll
            for (int ii = 0; ii < 4; ++ii) {
                float cross = ax[ii] * px[k] + ay[ii] * py[k] + az[ii] * pz[k];
                float d = an[ii] + bn - 2.0f * cross;
                d = fmaxf(d, 0.0f);
                if (d < best[ii]) { best[ii] = d; bidx[ii] = j; }  // first occurrence
            }
        }
    }

    __shared__ float sd[8][128];
    __shared__ int si[8][128];
#pragma unroll
    for (int ii = 0; ii < 4; ++ii) {
        sd[ig * 4 + ii][part] = best[ii];
        si[ig * 4 + ii][part] = bidx[ii];
    }
    __syncthreads();

    if (tid < 8) {
        int n = tile * 8 + tid;
        float bb = INFINITY;
        int bi = 0x7fffffff;
        for (int p = 0; p < 128; ++p) {
            float dv = sd[tid][p];
            int iv = si[tid][p];
            // explicit tie-break on smallest j (interleaved part sets)
            if (dv < bb || (dv == bb && iv < bi)) { bb = dv; bi = iv; }
        }
        idx_out[b * N_ + n] = bi;
        d2_out[b * N_ + n] = bb;

        // ---- inline prep for this n ----
        size_t i = (size_t)b * N_ + n;
        const float* g = pred_grasps + i * 16;
        float R[3][3] = {{g[0], g[1], g[2]}, {g[4], g[5], g[6]}, {g[8], g[9], g[10]}};
        float t[3] = {g[3], g[7], g[11]};

        float* P = Pout + i * 16;
        float pn = 0.0f;
#pragma unroll
        for (int c = 0; c < 5; ++c) {
            float cx = cp[c * 3], cy = cp[c * 3 + 1], cz = cp[c * 3 + 2];
#pragma unroll
            for (int kk = 0; kk < 3; ++kk) {
                float v = R[kk][0] * cx + R[kk][1] * cy + R[kk][2] * cz + t[kk];
                P[c * 3 + kk] = v;
                pn += v * v;
            }
        }
        P[15] = pn;

        bool succ = bb < R2_;
        float RL[3][3], TL[3];
        if (succ) {
            const float* rl = rot + ((size_t)b * M_ + bi) * 9;
#pragma unroll
            for (int a = 0; a < 3; ++a)
#pragma unroll
                for (int c2 = 0; c2 < 3; ++c2) RL[a][c2] = rl[a * 3 + c2];
            const float* tl = trans + ((size_t)b * M_ + bi) * 3;
            TL[0] = tl[0]; TL[1] = tl[1]; TL[2] = tl[2];
        } else {
#pragma unroll
            for (int a = 0; a < 3; ++a) {
#pragma unroll
                for (int c2 = 0; c2 < 3; ++c2) RL[a][c2] = FAR_;
                TL[a] = FAR_;
            }
        }

        // quad-SoA G write: comp c -> gtb[(c/4)*N_*4 + (c%4)]
        float* gtb = Gt + ((size_t)b * 8 * N_ + n) * 4;
        float gn = 0.0f, gsn = 0.0f;
#pragma unroll
        for (int c = 0; c < 5; ++c) {
            float cx = cp[c * 3], cy = cp[c * 3 + 1], cz = cp[c * 3 + 2];
#pragma unroll
            for (int kk = 0; kk < 3; ++kk) {
                int comp = c * 3 + kk;
                float v = RL[kk][0] * cx + RL[kk][1] * cy + RL[kk][2] * cz + TL[kk];
                gtb[(size_t)(comp >> 2) * (N_ * 4) + (comp & 3)] = v;
                gn += v * v;
            }
        }
        gtb[(size_t)(15 >> 2) * (N_ * 4) + (15 & 3)] = gn;
#pragma unroll
        for (int c = 0; c < 5; ++c) {
            float cx = cps[c * 3], cy = cps[c * 3 + 1], cz = cps[c * 3 + 2];
#pragma unroll
            for (int kk = 0; kk < 3; ++kk) {
                int comp = 16 + c * 3 + kk;
                float v = RL[kk][0] * cx + RL[kk][1] * cy + RL[kk][2] * cz + TL[kk];
                gtb[(size_t)(comp >> 2) * (N_ * 4) + (comp & 3)] = v;
                gsn += v * v;
            }
        }
        gtb[(size_t)(31 >> 2) * (N_ * 4) + (31 & 3)] = gsn;
    }
}

// ---------------------------------------------------------------------------
// K2: hard-negative selection (R6-measured structure, unchanged).
__global__ __launch_bounds__(256) void rank_kernel(const float* __restrict__ d2w,
                                                   float* __restrict__ selws) {
    int blk = blockIdx.x;
    int b = blk / (N_ / 16);
    int tile = blk % (N_ / 16);
    int tid = threadIdx.x;
    int n_local = tid & 15;
    int part = tid >> 4;              // 0..15

    __shared__ __align__(16) float pri[N_];
    __shared__ int cnt_sh[16][17];
    __shared__ int s_npos;
    if (tid == 0) s_npos = 0;
    __syncthreads();

    int lp = 0;
    for (int q = tid; q < N_; q += 256) {
        bool pos = d2w[b * N_ + q] < R2_;
        pri[q] = pos ? INFINITY : jax_uniform_r(b * N_ + q);
        if (pos) lp++;
    }
    atomicAdd(&s_npos, lp);
    __syncthreads();

    int n = tile * 16 + n_local;
    float ra = pri[n];

    int cnt = 0;
    const float4* p4 = reinterpret_cast<const float4*>(pri);
    for (int o = 0; o < 8; ++o) {
        float4 v[4];
#pragma unroll
        for (int k = 0; k < 4; ++k) v[k] = p4[part + (o * 4 + k) * 16];
#pragma unroll
        for (int k = 0; k < 4; ++k) {
            int qb = (part + (o * 4 + k) * 16) * 4;
            cnt += ((v[k].x < ra) || (v[k].x == ra && (qb + 0) < n)) ? 1 : 0;
            cnt += ((v[k].y < ra) || (v[k].y == ra && (qb + 1) < n)) ? 1 : 0;
            cnt += ((v[k].z < ra) || (v[k].z == ra && (qb + 2) < n)) ? 1 : 0;
            cnt += ((v[k].w < ra) || (v[k].w == ra && (qb + 3) < n)) ? 1 : 0;
        }
    }
    cnt_sh[part][n_local] = cnt;
    __syncthreads();

    if (tid < 16) {
        int tot = 0;
#pragma unroll
        for (int p = 0; p < 16; ++p) tot += cnt_sh[p][tid];
        int npos = s_npos;
        int kk = (npos > 0) ? npos : 2;
        int n2 = tile * 16 + tid;
        float r2 = pri[n2];
        selws[b * N_ + n2] = (r2 == INFINITY) ? 1.0f : ((tot < kk) ? 1.0f : 0.0f);
    }
}

// ---------------------------------------------------------------------------
// K3: ADD-S min with quad-SoA G, 4 i per wave (halves Gt L2 traffic vs R10).
// Grid = B*(N/16) = 512 blocks, 4 waves/block, block covers 16 i.
// Wave owns 4 i's; lane l handles j = jb*64 + l. Each quad load is a
// global_load_dwordx4 with lane-consecutive float4s (1KB/instr coalesced).
__global__ __launch_bounds__(256, 4) void adds_kernel(const float* __restrict__ Parr,
                                                      const float4* __restrict__ Gt4,
                                                      float* __restrict__ mOut) {
    int blk = blockIdx.x;
    int b = blk / (N_ / 16);
    int tile = blk % (N_ / 16);
    int w = threadIdx.x >> 6;              // wave 0..3
    int lane = threadIdx.x & 63;
    int i0 = tile * 16 + w * 4;

    const float4* P4 = reinterpret_cast<const float4*>(Parr) + ((size_t)b * N_ + i0) * 4;
    float Pv[4][16];
#pragma unroll
    for (int h = 0; h < 4; ++h)
#pragma unroll
        for (int q = 0; q < 4; ++q) {
            float4 v = P4[h * 4 + q];
            Pv[h][q * 4 + 0] = v.x; Pv[h][q * 4 + 1] = v.y;
            Pv[h][q * 4 + 2] = v.z; Pv[h][q * 4 + 3] = v.w;
        }

    const float4* gq = Gt4 + (size_t)b * 8 * N_;
    float best[4] = {INFINITY, INFINITY, INFINITY, INFINITY};
    for (int jb = 0; jb < N_ / 64; ++jb) {
        int j = jb * 64 + lane;
        float g[16];
        // half 1: quads 0..3 = comps 0..15 (G + norm)
        {
            float4 h0 = gq[(size_t)0 * N_ + j];
            float4 h1 = gq[(size_t)1 * N_ + j];
            float4 h2 = gq[(size_t)2 * N_ + j];
            float4 h3 = gq[(size_t)3 * N_ + j];
            g[0] = h0.x; g[1] = h0.y; g[2] = h0.z; g[3] = h0.w;
            g[4] = h1.x; g[5] = h1.y; g[6] = h1.z; g[7] = h1.w;
            g[8] = h2.x; g[9] = h2.y; g[10] = h2.z; g[11] = h2.w;
            g[12] = h3.x; g[13] = h3.y; g[14] = h3.z; g[15] = h3.w;
        }
        float s1[4];
        {
            float d[4] = {0.0f, 0.0f, 0.0f, 0.0f};
#pragma unroll
            for (int q = 0; q < 15; ++q)
#pragma unroll
                for (int ii = 0; ii < 4; ++ii) d[ii] += Pv[ii][q] * g[q];
#pragma unroll
            for (int ii = 0; ii < 4; ++ii) s1[ii] = Pv[ii][15] + g[15] - 2.0f * d[ii];
        }
        // half 2: quads 4..7 = comps 16..31 (Gs + norm)
        {
            float4 h0 = gq[(size_t)4 * N_ + j];
            float4 h1 = gq[(size_t)5 * N_ + j];
            float4 h2 = gq[(size_t)6 * N_ + j];
            float4 h3 = gq[(size_t)7 * N_ + j];
            g[0] = h0.x; g[1] = h0.y; g[2] = h0.z; g[3] = h0.w;
            g[4] = h1.x; g[5] = h1.y; g[6] = h1.z; g[7] = h1.w;
            g[8] = h2.x; g[9] = h2.y; g[10] = h2.z; g[11] = h2.w;
            g[12] = h3.x; g[13] = h3.y; g[14] = h3.z; g[15] = h3.w;
        }
        {
            float d[4] = {0.0f, 0.0f, 0.0f, 0.0f};
#pragma unroll
            for (int q = 0; q < 15; ++q)
#pragma unroll
                for (int ii = 0; ii < 4; ++ii) d[ii] += Pv[ii][q] * g[q];
#pragma unroll
            for (int ii = 0; ii < 4; ++ii) {
                float s2 = Pv[ii][15] + g[15] - 2.0f * d[ii];
                best[ii] = fminf(best[ii], fminf(s1[ii], s2));
            }
        }
    }
    // 64-lane min butterfly
#pragma unroll
    for (int m = 32; m > 0; m >>= 1) {
#pragma unroll
        for (int ii = 0; ii < 4; ++ii)
            best[ii] = fminf(best[ii], __shfl_xor(best[ii], m));
    }
    if (lane == 0) {
#pragma unroll
        for (int ii = 0; ii < 4; ++ii) mOut[b * N_ + i0 + ii] = best[ii];
    }
}

// ---------------------------------------------------------------------------
// K4: per-batch sums (R6-measured structure, unchanged). Grid = B*8 = 32
// blocks, 1 n per thread. Fixed-order partials + last-block combine.
__global__ __launch_bounds__(256) void finalize_kernel(
        const float* __restrict__ scores, const float* __restrict__ gwh,
        const float* __restrict__ pcw, const int* __restrict__ idxw,
        const float* __restrict__ d2w, const float* __restrict__ mw,
        const float* __restrict__ selws,
        float* __restrict__ partials, int* __restrict__ counters,
        float* __restrict__ out) {
    int fid = blockIdx.x;                  // 0..31
    int b = fid >> 3;
    int part = fid & 7;
    int tid = threadIdx.x;
    int n = part * 256 + tid;
    __shared__ float wsum[4][5];

    float sc = scores[b * N_ + n];
    float pcl = fminf(fmaxf(sc, EPS_), 0.9999999f);
    bool pos = d2w[b * N_ + n] < R2_;
    float s = pos ? 1.0f : 0.0f;
    float bce = -(s * logf(pcl) + (1.0f - s) * logf(1.0f - pcl));
    float selv = selws[b * N_ + n];
    float sum_sel = selv;
    float sum_bce = bce * selv;
    float sum_pos = s;
    float sum_wl = 0.0f, sum_adds = 0.0f;
    if (pos) {
        int jx = idxw[b * N_ + n];
        float w = pcw[b * M_ + jx];
        float acc = 0.0f;
#pragma unroll
        for (int jb = 0; jb < 10; ++jb) {
            float x = gwh[((size_t)b * 10 + jb) * N_ + n];
            float mh = (w >= c_LO[jb] && w < c_HI[jb]) ? 1.0f : 0.0f;
            float bw = fmaxf(x, 0.0f) - x * mh + log1pf(expf(-fabsf(x)));
            acc += c_BW[jb] * bw;
        }
        sum_wl = acc * 0.1f;
        float mv = mw[b * N_ + n];
        sum_adds = sc * sqrtf(fmaxf(mv, 0.0f) + 1e-12f);
    }

    // deterministic reduce: wave shuffle + per-wave LDS + thread-0 combine
    float v0 = sum_sel, v1 = sum_bce, v2 = sum_wl, v3 = sum_adds, v4 = sum_pos;
#pragma unroll
    for (int off = 32; off > 0; off >>= 1) {
        v0 += __shfl_down(v0, off);
        v1 += __shfl_down(v1, off);
        v2 += __shfl_down(v2, off);
        v3 += __shfl_down(v3, off);
        v4 += __shfl_down(v4, off);
    }
    int wv = tid >> 6, lane = tid & 63;
    if (lane == 0) {
        wsum[wv][0] = v0; wsum[wv][1] = v1; wsum[wv][2] = v2;
        wsum[wv][3] = v3; wsum[wv][4] = v4;
    }
    __syncthreads();
    if (tid == 0) {
        float t0 = 0, t1 = 0, t2 = 0, t3 = 0, t4 = 0;
#pragma unroll
        for (int w = 0; w < 4; ++w) {
            t0 += wsum[w][0]; t1 += wsum[w][1]; t2 += wsum[w][2];
            t3 += wsum[w][3]; t4 += wsum[w][4];
        }
        float* pp = partials + (size_t)fid * 5;
        pp[0] = t0; pp[1] = t1; pp[2] = t2; pp[3] = t3; pp[4] = t4;
        __threadfence();
        int old = atomicAdd(&counters[1], 1);
        if (old == 32 - 1) {
            __threadfence();
            float bin = 0, wid = 0, ad = 0;
#pragma unroll
            for (int b2 = 0; b2 < B_; ++b2) {
                float u0 = 0, u1 = 0, u2 = 0, u3 = 0, u4 = 0;
#pragma unroll
                for (int p2 = 0; p2 < 8; ++p2) {       // fixed order: deterministic
                    const float* q = partials + (size_t)(b2 * 8 + p2) * 5;
                    u0 += q[0]; u1 += q[1]; u2 += q[2]; u3 += q[3]; u4 += q[4];
                }
                float piv = fmaxf(u4, 1.0f);           // pos_in_view
                bin += u1 / fmaxf(u0, 1.0f);
                wid += u2 / piv;
                ad  += u3 / piv;
            }
            bin *= 0.25f; wid *= 0.25f; ad *= 0.25f;
            out[0] = bin + wid + 3.0f * ad;
            out[1] = bin;
            out[2] = wid;
            out[3] = ad;
        }
    }
}

// ---------------------------------------------------------------------------
extern "C" void kernel_launch(void* const* d_in, const int* in_sizes, int n_in,
                              void* d_out, int out_size, void* d_ws, size_t ws_size,
                              hipStream_t stream) {
    const float* pred_grasps = (const float*)d_in[0];   // (4,2048,4,4)
    const float* pred_scores = (const float*)d_in[1];   // (4,2048,1)
    const float* pred_points = (const float*)d_in[2];   // (4,2048,3)
    const float* gwh         = (const float*)d_in[3];   // (4,10,2048)
    const float* pcp         = (const float*)d_in[4];   // (4,4096,3)
    const float* pcw         = (const float*)d_in[5];   // (4,4096)
    const float* pcr         = (const float*)d_in[6];   // (4,4096,3,3)
    const float* pct         = (const float*)d_in[7];   // (4,4096,3)
    const float* cp          = (const float*)d_in[8];   // (1,5,3)
    const float* cps         = (const float*)d_in[9];   // (1,5,3)
    (void)in_sizes; (void)n_in; (void)out_size; (void)ws_size;

    float* ws = (float*)d_ws;
    int*   idxw  = (int*)ws;                            //   8192
    float* d2w   = ws + 8192;                           //   8192
    float* Pw    = ws + 16384;                          // 131072
    float* Gt    = Pw + 131072;                         // 262144 (quad-SoA)
    float* mw    = Gt + 262144;                         //   8192
    float* selws = mw + 8192;                           //   8192
    float* parts = selws + 8192;                        //    160
    int*   ctrs  = (int*)(parts + 160);                 //      2
    float* outp  = (float*)d_out;

    hipLaunchKernelGGL(nn_prep_kernel, dim3(B_ * (N_ / 8)), dim3(256), 0, stream,
                       pred_points, pcp, pred_grasps, pcr, pct, cp, cps,
                       idxw, d2w, Pw, Gt, ctrs);
    hipLaunchKernelGGL(rank_kernel, dim3(B_ * (N_ / 16)), dim3(256), 0, stream,
                       d2w, selws);
    hipLaunchKernelGGL(adds_kernel, dim3(B_ * (N_ / 16)), dim3(256), 0, stream,
                       Pw, (const float4*)Gt, mw);
    hipLaunchKernelGGL(finalize_kernel, dim3(B_ * 8), dim3(256), 0, stream,
                       pred_scores, gwh, pcw, idxw, d2w, mw, selws, parts, ctrs, outp);
}

// Round 13
// 150.952 us; speedup vs baseline: 1.1671x; 1.0700x over previous
//
#include <hip/hip_runtime.h>
#include <math.h>

#define B_ 4
#define N_ 2048
#define M_ 4096

// ---- constants (fp32 copies of the reference's) ----
__constant__ float c_LO[10] = {0.0f, 0.00794435329f, 0.0158887021f, 0.0238330509f,
                               0.0317773996f, 0.0397217484f, 0.0476660972f,
                               0.0556104459f, 0.0635547947f, 0.0714991435f};
__constant__ float c_HI[10] = {0.00794435329f, 0.0158887021f, 0.0238330509f,
                               0.0317773996f, 0.0397217484f, 0.0476660972f,
                               0.0556104459f, 0.0635547947f, 0.0714991435f, 0.08f};
__constant__ float c_BW[10] = {0.16652107f, 0.21488856f, 0.37031708f, 0.55618503f,
                               0.75124664f, 0.93943357f, 1.07824539f, 1.19423112f,
                               1.55731375f, 2.34173634f};

#define R2_ 2.5e-05f   // fp32(0.005**2) — matches JAX weak-type cast
#define FAR_ 100000.0f
#define EPS_ 1e-07f

// ---------------------------------------------------------------------------
// JAX threefry2x32, key = jax.random.key(42) -> (0, 42)
__device__ inline unsigned rotl32(unsigned x, int d) { return (x << d) | (x >> (32 - d)); }

__device__ inline void threefry2x32_42(unsigned x0, unsigned x1, unsigned& o0, unsigned& o1) {
    const unsigned k0 = 0u, k1 = 42u;
    const unsigned k2 = k0 ^ k1 ^ 0x1BD11BDAu;
    const unsigned ks[3] = {k0, k1, k2};
    const int rot[2][4] = {{13, 15, 26, 6}, {17, 29, 16, 24}};
    unsigned v0 = x0 + k0;
    unsigned v1 = x1 + k1;
#pragma unroll
    for (int i = 0; i < 5; ++i) {
        const int* r = rot[i & 1];
#pragma unroll
        for (int j = 0; j < 4; ++j) {
            v0 += v1;
            v1 = rotl32(v1, r[j]);
            v1 ^= v0;
        }
        v0 += ks[(i + 1) % 3];
        v1 += ks[(i + 2) % 3] + (unsigned)(i + 1);
    }
    o0 = v0; o1 = v1;
}

__device__ inline float bits_to_uniform(unsigned bits) {
    float f = __uint_as_float((bits >> 9) | 0x3f800000u) - 1.0f;
    return fmaxf(0.0f, f);
}

__device__ inline float jax_uniform_r(int flat) {
    unsigned o0, o1;
    if (flat < 4096) {
        threefry2x32_42((unsigned)flat, (unsigned)(flat + 4096), o0, o1);
        return bits_to_uniform(o0);
    } else {
        threefry2x32_42((unsigned)(flat - 4096), (unsigned)flat, o0, o1);
        return bits_to_uniform(o1);
    }
}

// ---------------------------------------------------------------------------
// K1: fused NN + prep (R10-measured structure: pcp read directly from d_in).
// Grid = B*(N/8) = 1024 blocks.
// G written in quad-SoA: comp c of (b,n) at Gt[((b*8+c/4)*N_+n)*4 + (c%4)].
__global__ __launch_bounds__(256, 4) void nn_prep_kernel(
        const float* __restrict__ ppts, const float* __restrict__ pcp,
        const float* __restrict__ pred_grasps,
        const float* __restrict__ rot, const float* __restrict__ trans,
        const float* __restrict__ cp, const float* __restrict__ cps,
        int* __restrict__ idx_out, float* __restrict__ d2_out,
        float* __restrict__ Pout, float* __restrict__ Gt,
        int* __restrict__ counters) {
    if (blockIdx.x == 0 && threadIdx.x == 0) { counters[0] = 0; counters[1] = 0; }
    int blk = blockIdx.x;
    int b = blk / (N_ / 8);
    int tile = blk % (N_ / 8);
    int tid = threadIdx.x;
    int ig = tid & 1;             // i-group: 4 consecutive i's
    int part = tid >> 1;          // 0..127
    int i0 = tile * 8 + ig * 4;

    float ax[4], ay[4], az[4], an[4];
#pragma unroll
    for (int ii = 0; ii < 4; ++ii) {
        const float* pp = ppts + ((size_t)b * N_ + i0 + ii) * 3;
        ax[ii] = pp[0]; ay[ii] = pp[1]; az[ii] = pp[2];
        an[ii] = ax[ii] * ax[ii] + ay[ii] * ay[ii] + az[ii] * az[ii];
    }

    const float4* pb4 = reinterpret_cast<const float4*>(pcp + (size_t)b * M_ * 3);
    float best[4] = {INFINITY, INFINITY, INFINITY, INFINITY};
    int bidx[4] = {0, 0, 0, 0};
    for (int g = 0; g < 8; ++g) {
        int grp = g * 128 + part;            // group of 4 contact points
        float4 q0 = pb4[grp * 3 + 0];
        float4 q1 = pb4[grp * 3 + 1];
        float4 q2 = pb4[grp * 3 + 2];
        float px[4] = {q0.x, q0.w, q1.z, q2.y};
        float py[4] = {q0.y, q1.x, q1.w, q2.z};
        float pz[4] = {q0.z, q1.y, q2.x, q2.w};
#pragma unroll
        for (int k = 0; k < 4; ++k) {
            float bn = px[k] * px[k] + py[k] * py[k] + pz[k] * pz[k];
            int j = grp * 4 + k;             // ascending within thread
#pragma unroll
            for (int ii = 0; ii < 4; ++ii) {
                float cross = ax[ii] * px[k] + ay[ii] * py[k] + az[ii] * pz[k];
                float d = an[ii] + bn - 2.0f * cross;
                d = fmaxf(d, 0.0f);
                if (d < best[ii]) { best[ii] = d; bidx[ii] = j; }  // first occurrence
            }
        }
    }

    __shared__ float sd[8][128];
    __shared__ int si[8][128];
#pragma unroll
    for (int ii = 0; ii < 4; ++ii) {
        sd[ig * 4 + ii][part] = best[ii];
        si[ig * 4 + ii][part] = bidx[ii];
    }
    __syncthreads();

    if (tid < 8) {
        int n = tile * 8 + tid;
        float bb = INFINITY;
        int bi = 0x7fffffff;
        for (int p = 0; p < 128; ++p) {
            float dv = sd[tid][p];
            int iv = si[tid][p];
            // explicit tie-break on smallest j (interleaved part sets)
            if (dv < bb || (dv == bb && iv < bi)) { bb = dv; bi = iv; }
        }
        idx_out[b * N_ + n] = bi;
        d2_out[b * N_ + n] = bb;

        // ---- inline prep for this n ----
        size_t i = (size_t)b * N_ + n;
        const float* g = pred_grasps + i * 16;
        float R[3][3] = {{g[0], g[1], g[2]}, {g[4], g[5], g[6]}, {g[8], g[9], g[10]}};
        float t[3] = {g[3], g[7], g[11]};

        float* P = Pout + i * 16;
        float pn = 0.0f;
#pragma unroll
        for (int c = 0; c < 5; ++c) {
            float cx = cp[c * 3], cy = cp[c * 3 + 1], cz = cp[c * 3 + 2];
#pragma unroll
            for (int kk = 0; kk < 3; ++kk) {
                float v = R[kk][0] * cx + R[kk][1] * cy + R[kk][2] * cz + t[kk];
                P[c * 3 + kk] = v;
                pn += v * v;
            }
        }
        P[15] = pn;

        bool succ = bb < R2_;
        float RL[3][3], TL[3];
        if (succ) {
            const float* rl = rot + ((size_t)b * M_ + bi) * 9;
#pragma unroll
            for (int a = 0; a < 3; ++a)
#pragma unroll
                for (int c2 = 0; c2 < 3; ++c2) RL[a][c2] = rl[a * 3 + c2];
            const float* tl = trans + ((size_t)b * M_ + bi) * 3;
            TL[0] = tl[0]; TL[1] = tl[1]; TL[2] = tl[2];
        } else {
#pragma unroll
            for (int a = 0; a < 3; ++a) {
#pragma unroll
                for (int c2 = 0; c2 < 3; ++c2) RL[a][c2] = FAR_;
                TL[a] = FAR_;
            }
        }

        // quad-SoA G write: comp c -> gtb[(c/4)*N_*4 + (c%4)]
        float* gtb = Gt + ((size_t)b * 8 * N_ + n) * 4;
        float gn = 0.0f, gsn = 0.0f;
#pragma unroll
        for (int c = 0; c < 5; ++c) {
            float cx = cp[c * 3], cy = cp[c * 3 + 1], cz = cp[c * 3 + 2];
#pragma unroll
            for (int kk = 0; kk < 3; ++kk) {
                int comp = c * 3 + kk;
                float v = RL[kk][0] * cx + RL[kk][1] * cy + RL[kk][2] * cz + TL[kk];
                gtb[(size_t)(comp >> 2) * (N_ * 4) + (comp & 3)] = v;
                gn += v * v;
            }
        }
        gtb[(size_t)(15 >> 2) * (N_ * 4) + (15 & 3)] = gn;
#pragma unroll
        for (int c = 0; c < 5; ++c) {
            float cx = cps[c * 3], cy = cps[c * 3 + 1], cz = cps[c * 3 + 2];
#pragma unroll
            for (int kk = 0; kk < 3; ++kk) {
                int comp = 16 + c * 3 + kk;
                float v = RL[kk][0] * cx + RL[kk][1] * cy + RL[kk][2] * cz + TL[kk];
                gtb[(size_t)(comp >> 2) * (N_ * 4) + (comp & 3)] = v;
                gsn += v * v;
            }
        }
        gtb[(size_t)(31 >> 2) * (N_ * 4) + (31 & 3)] = gsn;
    }
}

// ---------------------------------------------------------------------------
// K2: hard-negative selection (R6-measured structure, unchanged).
__global__ __launch_bounds__(256) void rank_kernel(const float* __restrict__ d2w,
                                                   float* __restrict__ selws) {
    int blk = blockIdx.x;
    int b = blk / (N_ / 16);
    int tile = blk % (N_ / 16);
    int tid = threadIdx.x;
    int n_local = tid & 15;
    int part = tid >> 4;              // 0..15

    __shared__ __align__(16) float pri[N_];
    __shared__ int cnt_sh[16][17];
    __shared__ int s_npos;
    if (tid == 0) s_npos = 0;
    __syncthreads();

    int lp = 0;
    for (int q = tid; q < N_; q += 256) {
        bool pos = d2w[b * N_ + q] < R2_;
        pri[q] = pos ? INFINITY : jax_uniform_r(b * N_ + q);
        if (pos) lp++;
    }
    atomicAdd(&s_npos, lp);
    __syncthreads();

    int n = tile * 16 + n_local;
    float ra = pri[n];

    int cnt = 0;
    const float4* p4 = reinterpret_cast<const float4*>(pri);
    for (int o = 0; o < 8; ++o) {
        float4 v[4];
#pragma unroll
        for (int k = 0; k < 4; ++k) v[k] = p4[part + (o * 4 + k) * 16];
#pragma unroll
        for (int k = 0; k < 4; ++k) {
            int qb = (part + (o * 4 + k) * 16) * 4;
            cnt += ((v[k].x < ra) || (v[k].x == ra && (qb + 0) < n)) ? 1 : 0;
            cnt += ((v[k].y < ra) || (v[k].y == ra && (qb + 1) < n)) ? 1 : 0;
            cnt += ((v[k].z < ra) || (v[k].z == ra && (qb + 2) < n)) ? 1 : 0;
            cnt += ((v[k].w < ra) || (v[k].w == ra && (qb + 3) < n)) ? 1 : 0;
        }
    }
    cnt_sh[part][n_local] = cnt;
    __syncthreads();

    if (tid < 16) {
        int tot = 0;
#pragma unroll
        for (int p = 0; p < 16; ++p) tot += cnt_sh[p][tid];
        int npos = s_npos;
        int kk = (npos > 0) ? npos : 2;
        int n2 = tile * 16 + tid;
        float r2 = pri[n2];
        selws[b * N_ + n2] = (r2 == INFINITY) ? 1.0f : ((tot < kk) ? 1.0f : 0.0f);
    }
}

// ---------------------------------------------------------------------------
// K3: ADD-S min, quad-SoA G, 4 i per wave, j-split across 2 blocks.
// Grid = B*(N/16)*2 = 1024 blocks (4 blocks/CU). Block covers 16 i and half
// the j-range (1024 j). Partial minima written to mw2[idx*2 + jh]; finalize
// combines with one fminf (min over disjoint subsets == global min, exact).
__global__ __launch_bounds__(256, 4) void adds_kernel(const float* __restrict__ Parr,
                                                      const float4* __restrict__ Gt4,
                                                      float* __restrict__ mOut2) {
    int blk = blockIdx.x;
    int b = blk / (2 * (N_ / 16));
    int rem = blk % (2 * (N_ / 16));
    int tile = rem >> 1;
    int jh = rem & 1;                      // j-half
    int w = threadIdx.x >> 6;              // wave 0..3
    int lane = threadIdx.x & 63;
    int i0 = tile * 16 + w * 4;

    const float4* P4 = reinterpret_cast<const float4*>(Parr) + ((size_t)b * N_ + i0) * 4;
    float Pv[4][16];
#pragma unroll
    for (int h = 0; h < 4; ++h)
#pragma unroll
        for (int q = 0; q < 4; ++q) {
            float4 v = P4[h * 4 + q];
            Pv[h][q * 4 + 0] = v.x; Pv[h][q * 4 + 1] = v.y;
            Pv[h][q * 4 + 2] = v.z; Pv[h][q * 4 + 3] = v.w;
        }

    const float4* gq = Gt4 + (size_t)b * 8 * N_;
    float best[4] = {INFINITY, INFINITY, INFINITY, INFINITY};
    int jb0 = jh * (N_ / 128);             // 16 iterations per half
    for (int jb = jb0; jb < jb0 + (N_ / 128); ++jb) {
        int j = jb * 64 + lane;
        float g[16];
        // half 1: quads 0..3 = comps 0..15 (G + norm)
        {
            float4 h0 = gq[(size_t)0 * N_ + j];
            float4 h1 = gq[(size_t)1 * N_ + j];
            float4 h2 = gq[(size_t)2 * N_ + j];
            float4 h3 = gq[(size_t)3 * N_ + j];
            g[0] = h0.x; g[1] = h0.y; g[2] = h0.z; g[3] = h0.w;
            g[4] = h1.x; g[5] = h1.y; g[6] = h1.z; g[7] = h1.w;
            g[8] = h2.x; g[9] = h2.y; g[10] = h2.z; g[11] = h2.w;
            g[12] = h3.x; g[13] = h3.y; g[14] = h3.z; g[15] = h3.w;
        }
        float s1[4];
        {
            float d[4] = {0.0f, 0.0f, 0.0f, 0.0f};
#pragma unroll
            for (int q = 0; q < 15; ++q)
#pragma unroll
                for (int ii = 0; ii < 4; ++ii) d[ii] += Pv[ii][q] * g[q];
#pragma unroll
            for (int ii = 0; ii < 4; ++ii) s1[ii] = Pv[ii][15] + g[15] - 2.0f * d[ii];
        }
        // half 2: quads 4..7 = comps 16..31 (Gs + norm)
        {
            float4 h0 = gq[(size_t)4 * N_ + j];
            float4 h1 = gq[(size_t)5 * N_ + j];
            float4 h2 = gq[(size_t)6 * N_ + j];
            float4 h3 = gq[(size_t)7 * N_ + j];
            g[0] = h0.x; g[1] = h0.y; g[2] = h0.z; g[3] = h0.w;
            g[4] = h1.x; g[5] = h1.y; g[6] = h1.z; g[7] = h1.w;
            g[8] = h2.x; g[9] = h2.y; g[10] = h2.z; g[11] = h2.w;
            g[12] = h3.x; g[13] = h3.y; g[14] = h3.z; g[15] = h3.w;
        }
        {
            float d[4] = {0.0f, 0.0f, 0.0f, 0.0f};
#pragma unroll
            for (int q = 0; q < 15; ++q)
#pragma unroll
                for (int ii = 0; ii < 4; ++ii) d[ii] += Pv[ii][q] * g[q];
#pragma unroll
            for (int ii = 0; ii < 4; ++ii) {
                float s2 = Pv[ii][15] + g[15] - 2.0f * d[ii];
                best[ii] = fminf(best[ii], fminf(s1[ii], s2));
            }
        }
    }
    // 64-lane min butterfly
#pragma unroll
    for (int m = 32; m > 0; m >>= 1) {
#pragma unroll
        for (int ii = 0; ii < 4; ++ii)
            best[ii] = fminf(best[ii], __shfl_xor(best[ii], m));
    }
    if (lane == 0) {
#pragma unroll
        for (int ii = 0; ii < 4; ++ii)
            mOut2[(size_t)(b * N_ + i0 + ii) * 2 + jh] = best[ii];
    }
}

// ---------------------------------------------------------------------------
// K4: per-batch sums (R6-measured structure; mw read combines 2 j-halves).
// Grid = B*8 = 32 blocks, 1 n per thread. Fixed-order partials + combine.
__global__ __launch_bounds__(256) void finalize_kernel(
        const float* __restrict__ scores, const float* __restrict__ gwh,
        const float* __restrict__ pcw, const int* __restrict__ idxw,
        const float* __restrict__ d2w, const float* __restrict__ mw2,
        const float* __restrict__ selws,
        float* __restrict__ partials, int* __restrict__ counters,
        float* __restrict__ out) {
    int fid = blockIdx.x;                  // 0..31
    int b = fid >> 3;
    int part = fid & 7;
    int tid = threadIdx.x;
    int n = part * 256 + tid;
    __shared__ float wsum[4][5];

    float sc = scores[b * N_ + n];
    float pcl = fminf(fmaxf(sc, EPS_), 0.9999999f);
    bool pos = d2w[b * N_ + n] < R2_;
    float s = pos ? 1.0f : 0.0f;
    float bce = -(s * logf(pcl) + (1.0f - s) * logf(1.0f - pcl));
    float selv = selws[b * N_ + n];
    float sum_sel = selv;
    float sum_bce = bce * selv;
    float sum_pos = s;
    float sum_wl = 0.0f, sum_adds = 0.0f;
    if (pos) {
        int jx = idxw[b * N_ + n];
        float w = pcw[b * M_ + jx];
        float acc = 0.0f;
#pragma unroll
        for (int jb = 0; jb < 10; ++jb) {
            float x = gwh[((size_t)b * 10 + jb) * N_ + n];
            float mh = (w >= c_LO[jb] && w < c_HI[jb]) ? 1.0f : 0.0f;
            float bw = fmaxf(x, 0.0f) - x * mh + log1pf(expf(-fabsf(x)));
            acc += c_BW[jb] * bw;
        }
        sum_wl = acc * 0.1f;
        float mv = fminf(mw2[(size_t)(b * N_ + n) * 2 + 0],
                         mw2[(size_t)(b * N_ + n) * 2 + 1]);
        sum_adds = sc * sqrtf(fmaxf(mv, 0.0f) + 1e-12f);
    }

    // deterministic reduce: wave shuffle + per-wave LDS + thread-0 combine
    float v0 = sum_sel, v1 = sum_bce, v2 = sum_wl, v3 = sum_adds, v4 = sum_pos;
#pragma unroll
    for (int off = 32; off > 0; off >>= 1) {
        v0 += __shfl_down(v0, off);
        v1 += __shfl_down(v1, off);
        v2 += __shfl_down(v2, off);
        v3 += __shfl_down(v3, off);
        v4 += __shfl_down(v4, off);
    }
    int wv = tid >> 6, lane = tid & 63;
    if (lane == 0) {
        wsum[wv][0] = v0; wsum[wv][1] = v1; wsum[wv][2] = v2;
        wsum[wv][3] = v3; wsum[wv][4] = v4;
    }
    __syncthreads();
    if (tid == 0) {
        float t0 = 0, t1 = 0, t2 = 0, t3 = 0, t4 = 0;
#pragma unroll
        for (int w = 0; w < 4; ++w) {
            t0 += wsum[w][0]; t1 += wsum[w][1]; t2 += wsum[w][2];
            t3 += wsum[w][3]; t4 += wsum[w][4];
        }
        float* pp = partials + (size_t)fid * 5;
        pp[0] = t0; pp[1] = t1; pp[2] = t2; pp[3] = t3; pp[4] = t4;
        __threadfence();
        int old = atomicAdd(&counters[1], 1);
        if (old == 32 - 1) {
            __threadfence();
            float bin = 0, wid = 0, ad = 0;
#pragma unroll
            for (int b2 = 0; b2 < B_; ++b2) {
                float u0 = 0, u1 = 0, u2 = 0, u3 = 0, u4 = 0;
#pragma unroll
                for (int p2 = 0; p2 < 8; ++p2) {       // fixed order: deterministic
                    const float* q = partials + (size_t)(b2 * 8 + p2) * 5;
                    u0 += q[0]; u1 += q[1]; u2 += q[2]; u3 += q[3]; u4 += q[4];
                }
                float piv = fmaxf(u4, 1.0f);           // pos_in_view
                bin += u1 / fmaxf(u0, 1.0f);
                wid += u2 / piv;
                ad  += u3 / piv;
            }
            bin *= 0.25f; wid *= 0.25f; ad *= 0.25f;
            out[0] = bin + wid + 3.0f * ad;
            out[1] = bin;
            out[2] = wid;
            out[3] = ad;
        }
    }
}

// ---------------------------------------------------------------------------
extern "C" void kernel_launch(void* const* d_in, const int* in_sizes, int n_in,
                              void* d_out, int out_size, void* d_ws, size_t ws_size,
                              hipStream_t stream) {
    const float* pred_grasps = (const float*)d_in[0];   // (4,2048,4,4)
    const float* pred_scores = (const float*)d_in[1];   // (4,2048,1)
    const float* pred_points = (const float*)d_in[2];   // (4,2048,3)
    const float* gwh         = (const float*)d_in[3];   // (4,10,2048)
    const float* pcp         = (const float*)d_in[4];   // (4,4096,3)
    const float* pcw         = (const float*)d_in[5];   // (4,4096)
    const float* pcr         = (const float*)d_in[6];   // (4,4096,3,3)
    const float* pct         = (const float*)d_in[7];   // (4,4096,3)
    const float* cp          = (const float*)d_in[8];   // (1,5,3)
    const float* cps         = (const float*)d_in[9];   // (1,5,3)
    (void)in_sizes; (void)n_in; (void)out_size; (void)ws_size;

    float* ws = (float*)d_ws;
    int*   idxw  = (int*)ws;                            //   8192
    float* d2w   = ws + 8192;                           //   8192
    float* Pw    = ws + 16384;                          // 131072
    float* Gt    = Pw + 131072;                         // 262144 (quad-SoA)
    float* mw2   = Gt + 262144;                         //  16384 (2 j-halves)
    float* selws = mw2 + 16384;                         //   8192
    float* parts = selws + 8192;                        //    160
    int*   ctrs  = (int*)(parts + 160);                 //      2
    float* outp  = (float*)d_out;

    hipLaunchKernelGGL(nn_prep_kernel, dim3(B_ * (N_ / 8)), dim3(256), 0, stream,
                       pred_points, pcp, pred_grasps, pcr, pct, cp, cps,
                       idxw, d2w, Pw, Gt, ctrs);
    hipLaunchKernelGGL(rank_kernel, dim3(B_ * (N_ / 16)), dim3(256), 0, stream,
                       d2w, selws);
    hipLaunchKernelGGL(adds_kernel, dim3(B_ * (N_ / 16) * 2), dim3(256), 0, stream,
                       Pw, (const float4*)Gt, mw2);
    hipLaunchKernelGGL(finalize_kernel, dim3(B_ * 8), dim3(256), 0, stream,
                       pred_scores, gwh, pcw, idxw, d2w, mw2, selws, parts, ctrs, outp);
}

// Round 14
// 140.973 us; speedup vs baseline: 1.2497x; 1.0708x over previous
//
#include <hip/hip_runtime.h>
#include <math.h>

#define B_ 4
#define N_ 2048
#define M_ 4096

#define ADDS_BLOCKS (B_ * (N_ / 16) * 2)   // 1024 (j-split x2)
#define RANK_BLOCKS (B_ * (N_ / 16))       // 512

// ---- constants (fp32 copies of the reference's) ----
__constant__ float c_LO[10] = {0.0f, 0.00794435329f, 0.0158887021f, 0.0238330509f,
                               0.0317773996f, 0.0397217484f, 0.0476660972f,
                               0.0556104459f, 0.0635547947f, 0.0714991435f};
__constant__ float c_HI[10] = {0.00794435329f, 0.0158887021f, 0.0238330509f,
                               0.0317773996f, 0.0397217484f, 0.0476660972f,
                               0.0556104459f, 0.0635547947f, 0.0714991435f, 0.08f};
__constant__ float c_BW[10] = {0.16652107f, 0.21488856f, 0.37031708f, 0.55618503f,
                               0.75124664f, 0.93943357f, 1.07824539f, 1.19423112f,
                               1.55731375f, 2.34173634f};

#define R2_ 2.5e-05f   // fp32(0.005**2) — matches JAX weak-type cast
#define FAR_ 100000.0f
#define EPS_ 1e-07f

// ---------------------------------------------------------------------------
// JAX threefry2x32, key = jax.random.key(42) -> (0, 42)
__device__ inline unsigned rotl32(unsigned x, int d) { return (x << d) | (x >> (32 - d)); }

__device__ inline void threefry2x32_42(unsigned x0, unsigned x1, unsigned& o0, unsigned& o1) {
    const unsigned k0 = 0u, k1 = 42u;
    const unsigned k2 = k0 ^ k1 ^ 0x1BD11BDAu;
    const unsigned ks[3] = {k0, k1, k2};
    const int rot[2][4] = {{13, 15, 26, 6}, {17, 29, 16, 24}};
    unsigned v0 = x0 + k0;
    unsigned v1 = x1 + k1;
#pragma unroll
    for (int i = 0; i < 5; ++i) {
        const int* r = rot[i & 1];
#pragma unroll
        for (int j = 0; j < 4; ++j) {
            v0 += v1;
            v1 = rotl32(v1, r[j]);
            v1 ^= v0;
        }
        v0 += ks[(i + 1) % 3];
        v1 += ks[(i + 2) % 3] + (unsigned)(i + 1);
    }
    o0 = v0; o1 = v1;
}

__device__ inline float bits_to_uniform(unsigned bits) {
    float f = __uint_as_float((bits >> 9) | 0x3f800000u) - 1.0f;
    return fmaxf(0.0f, f);
}

__device__ inline float jax_uniform_r(int flat) {
    unsigned o0, o1;
    if (flat < 4096) {
        threefry2x32_42((unsigned)flat, (unsigned)(flat + 4096), o0, o1);
        return bits_to_uniform(o0);
    } else {
        threefry2x32_42((unsigned)(flat - 4096), (unsigned)flat, o0, o1);
        return bits_to_uniform(o1);
    }
}

// ---------------------------------------------------------------------------
// K1: fused NN + prep (R10/R13-measured structure: pcp read directly from d_in).
// Grid = B*(N/8) = 1024 blocks.
// G written in quad-SoA: comp c of (b,n) at Gt[((b*8+c/4)*N_+n)*4 + (c%4)].
__global__ __launch_bounds__(256, 4) void nn_prep_kernel(
        const float* __restrict__ ppts, const float* __restrict__ pcp,
        const float* __restrict__ pred_grasps,
        const float* __restrict__ rot, const float* __restrict__ trans,
        const float* __restrict__ cp, const float* __restrict__ cps,
        int* __restrict__ idx_out, float* __restrict__ d2_out,
        float* __restrict__ Pout, float* __restrict__ Gt,
        int* __restrict__ counters) {
    if (blockIdx.x == 0 && threadIdx.x == 0) { counters[0] = 0; counters[1] = 0; }
    int blk = blockIdx.x;
    int b = blk / (N_ / 8);
    int tile = blk % (N_ / 8);
    int tid = threadIdx.x;
    int ig = tid & 1;             // i-group: 4 consecutive i's
    int part = tid >> 1;          // 0..127
    int i0 = tile * 8 + ig * 4;

    float ax[4], ay[4], az[4], an[4];
#pragma unroll
    for (int ii = 0; ii < 4; ++ii) {
        const float* pp = ppts + ((size_t)b * N_ + i0 + ii) * 3;
        ax[ii] = pp[0]; ay[ii] = pp[1]; az[ii] = pp[2];
        an[ii] = ax[ii] * ax[ii] + ay[ii] * ay[ii] + az[ii] * az[ii];
    }

    const float4* pb4 = reinterpret_cast<const float4*>(pcp + (size_t)b * M_ * 3);
    float best[4] = {INFINITY, INFINITY, INFINITY, INFINITY};
    int bidx[4] = {0, 0, 0, 0};
    for (int g = 0; g < 8; ++g) {
        int grp = g * 128 + part;            // group of 4 contact points
        float4 q0 = pb4[grp * 3 + 0];
        float4 q1 = pb4[grp * 3 + 1];
        float4 q2 = pb4[grp * 3 + 2];
        float px[4] = {q0.x, q0.w, q1.z, q2.y};
        float py[4] = {q0.y, q1.x, q1.w, q2.z};
        float pz[4] = {q0.z, q1.y, q2.x, q2.w};
#pragma unroll
        for (int k = 0; k < 4; ++k) {
            float bn = px[k] * px[k] + py[k] * py[k] + pz[k] * pz[k];
            int j = grp * 4 + k;             // ascending within thread
#pragma unroll
            for (int ii = 0; ii < 4; ++ii) {
                float cross = ax[ii] * px[k] + ay[ii] * py[k] + az[ii] * pz[k];
                float d = an[ii] + bn - 2.0f * cross;
                d = fmaxf(d, 0.0f);
                if (d < best[ii]) { best[ii] = d; bidx[ii] = j; }  // first occurrence
            }
        }
    }

    __shared__ float sd[8][128];
    __shared__ int si[8][128];
#pragma unroll
    for (int ii = 0; ii < 4; ++ii) {
        sd[ig * 4 + ii][part] = best[ii];
        si[ig * 4 + ii][part] = bidx[ii];
    }
    __syncthreads();

    if (tid < 8) {
        int n = tile * 8 + tid;
        float bb = INFINITY;
        int bi = 0x7fffffff;
        for (int p = 0; p < 128; ++p) {
            float dv = sd[tid][p];
            int iv = si[tid][p];
            // explicit tie-break on smallest j (interleaved part sets)
            if (dv < bb || (dv == bb && iv < bi)) { bb = dv; bi = iv; }
        }
        idx_out[b * N_ + n] = bi;
        d2_out[b * N_ + n] = bb;

        // ---- inline prep for this n ----
        size_t i = (size_t)b * N_ + n;
        const float* g = pred_grasps + i * 16;
        float R[3][3] = {{g[0], g[1], g[2]}, {g[4], g[5], g[6]}, {g[8], g[9], g[10]}};
        float t[3] = {g[3], g[7], g[11]};

        float* P = Pout + i * 16;
        float pn = 0.0f;
#pragma unroll
        for (int c = 0; c < 5; ++c) {
            float cx = cp[c * 3], cy = cp[c * 3 + 1], cz = cp[c * 3 + 2];
#pragma unroll
            for (int kk = 0; kk < 3; ++kk) {
                float v = R[kk][0] * cx + R[kk][1] * cy + R[kk][2] * cz + t[kk];
                P[c * 3 + kk] = v;
                pn += v * v;
            }
        }
        P[15] = pn;

        bool succ = bb < R2_;
        float RL[3][3], TL[3];
        if (succ) {
            const float* rl = rot + ((size_t)b * M_ + bi) * 9;
#pragma unroll
            for (int a = 0; a < 3; ++a)
#pragma unroll
                for (int c2 = 0; c2 < 3; ++c2) RL[a][c2] = rl[a * 3 + c2];
            const float* tl = trans + ((size_t)b * M_ + bi) * 3;
            TL[0] = tl[0]; TL[1] = tl[1]; TL[2] = tl[2];
        } else {
#pragma unroll
            for (int a = 0; a < 3; ++a) {
#pragma unroll
                for (int c2 = 0; c2 < 3; ++c2) RL[a][c2] = FAR_;
                TL[a] = FAR_;
            }
        }

        // quad-SoA G write: comp c -> gtb[(c/4)*N_*4 + (c%4)]
        float* gtb = Gt + ((size_t)b * 8 * N_ + n) * 4;
        float gn = 0.0f, gsn = 0.0f;
#pragma unroll
        for (int c = 0; c < 5; ++c) {
            float cx = cp[c * 3], cy = cp[c * 3 + 1], cz = cp[c * 3 + 2];
#pragma unroll
            for (int kk = 0; kk < 3; ++kk) {
                int comp = c * 3 + kk;
                float v = RL[kk][0] * cx + RL[kk][1] * cy + RL[kk][2] * cz + TL[kk];
                gtb[(size_t)(comp >> 2) * (N_ * 4) + (comp & 3)] = v;
                gn += v * v;
            }
        }
        gtb[(size_t)(15 >> 2) * (N_ * 4) + (15 & 3)] = gn;
#pragma unroll
        for (int c = 0; c < 5; ++c) {
            float cx = cps[c * 3], cy = cps[c * 3 + 1], cz = cps[c * 3 + 2];
#pragma unroll
            for (int kk = 0; kk < 3; ++kk) {
                int comp = 16 + c * 3 + kk;
                float v = RL[kk][0] * cx + RL[kk][1] * cy + RL[kk][2] * cz + TL[kk];
                gtb[(size_t)(comp >> 2) * (N_ * 4) + (comp & 3)] = v;
                gsn += v * v;
            }
        }
        gtb[(size_t)(31 >> 2) * (N_ * 4) + (31 & 3)] = gsn;
    }
}

// ---------------------------------------------------------------------------
// K2: merged adds + rank (both depend only on K1; independent roles, no waits).
//   [0, 1024):    ADD-S min, quad-SoA G, 4 i/wave, j-split (R13-measured)
//   [1024, 1536): hard-negative selection (R6-measured)
__global__ __launch_bounds__(256, 4) void work_kernel(
        const float* __restrict__ Parr, const float4* __restrict__ Gt4,
        float* __restrict__ mOut2,
        const float* __restrict__ d2w, float* __restrict__ selws) {
    __shared__ __align__(16) char smem[9600];
    int bid = blockIdx.x;
    int tid = threadIdx.x;

    if (bid < ADDS_BLOCKS) {
        // ================= adds role (R13 verbatim) =================
        int b = bid / (2 * (N_ / 16));
        int rem = bid % (2 * (N_ / 16));
        int tile = rem >> 1;
        int jh = rem & 1;                      // j-half
        int w = tid >> 6;                      // wave 0..3
        int lane = tid & 63;
        int i0 = tile * 16 + w * 4;

        const float4* P4 = reinterpret_cast<const float4*>(Parr) +
                           ((size_t)b * N_ + i0) * 4;
        float Pv[4][16];
#pragma unroll
        for (int h = 0; h < 4; ++h)
#pragma unroll
            for (int q = 0; q < 4; ++q) {
                float4 v = P4[h * 4 + q];
                Pv[h][q * 4 + 0] = v.x; Pv[h][q * 4 + 1] = v.y;
                Pv[h][q * 4 + 2] = v.z; Pv[h][q * 4 + 3] = v.w;
            }

        const float4* gq = Gt4 + (size_t)b * 8 * N_;
        float best[4] = {INFINITY, INFINITY, INFINITY, INFINITY};
        int jb0 = jh * (N_ / 128);             // 16 iterations per half
        for (int jb = jb0; jb < jb0 + (N_ / 128); ++jb) {
            int j = jb * 64 + lane;
            float g[16];
            // half 1: quads 0..3 = comps 0..15 (G + norm)
            {
                float4 h0 = gq[(size_t)0 * N_ + j];
                float4 h1 = gq[(size_t)1 * N_ + j];
                float4 h2 = gq[(size_t)2 * N_ + j];
                float4 h3 = gq[(size_t)3 * N_ + j];
                g[0] = h0.x; g[1] = h0.y; g[2] = h0.z; g[3] = h0.w;
                g[4] = h1.x; g[5] = h1.y; g[6] = h1.z; g[7] = h1.w;
                g[8] = h2.x; g[9] = h2.y; g[10] = h2.z; g[11] = h2.w;
                g[12] = h3.x; g[13] = h3.y; g[14] = h3.z; g[15] = h3.w;
            }
            float s1[4];
            {
                float d[4] = {0.0f, 0.0f, 0.0f, 0.0f};
#pragma unroll
                for (int q = 0; q < 15; ++q)
#pragma unroll
                    for (int ii = 0; ii < 4; ++ii) d[ii] += Pv[ii][q] * g[q];
#pragma unroll
                for (int ii = 0; ii < 4; ++ii) s1[ii] = Pv[ii][15] + g[15] - 2.0f * d[ii];
            }
            // half 2: quads 4..7 = comps 16..31 (Gs + norm)
            {
                float4 h0 = gq[(size_t)4 * N_ + j];
                float4 h1 = gq[(size_t)5 * N_ + j];
                float4 h2 = gq[(size_t)6 * N_ + j];
                float4 h3 = gq[(size_t)7 * N_ + j];
                g[0] = h0.x; g[1] = h0.y; g[2] = h0.z; g[3] = h0.w;
                g[4] = h1.x; g[5] = h1.y; g[6] = h1.z; g[7] = h1.w;
                g[8] = h2.x; g[9] = h2.y; g[10] = h2.z; g[11] = h2.w;
                g[12] = h3.x; g[13] = h3.y; g[14] = h3.z; g[15] = h3.w;
            }
            {
                float d[4] = {0.0f, 0.0f, 0.0f, 0.0f};
#pragma unroll
                for (int q = 0; q < 15; ++q)
#pragma unroll
                    for (int ii = 0; ii < 4; ++ii) d[ii] += Pv[ii][q] * g[q];
#pragma unroll
                for (int ii = 0; ii < 4; ++ii) {
                    float s2 = Pv[ii][15] + g[15] - 2.0f * d[ii];
                    best[ii] = fminf(best[ii], fminf(s1[ii], s2));
                }
            }
        }
        // 64-lane min butterfly
#pragma unroll
        for (int m = 32; m > 0; m >>= 1) {
#pragma unroll
            for (int ii = 0; ii < 4; ++ii)
                best[ii] = fminf(best[ii], __shfl_xor(best[ii], m));
        }
        if (lane == 0) {
#pragma unroll
            for (int ii = 0; ii < 4; ++ii)
                mOut2[(size_t)(b * N_ + i0 + ii) * 2 + jh] = best[ii];
        }
    } else {
        // ================= rank role (R6 verbatim) =================
        int rid = bid - ADDS_BLOCKS;
        int b = rid / (N_ / 16);
        int tile = rid % (N_ / 16);
        int n_local = tid & 15;
        int part = tid >> 4;               // 0..15

        float* pri = (float*)smem;                   // [2048] floats
        int* cnt_sh = (int*)(smem + 8192);           // [16][17]
        __shared__ int s_npos;
        if (tid == 0) s_npos = 0;
        __syncthreads();

        int lp = 0;
        for (int q = tid; q < N_; q += 256) {
            bool pos = d2w[b * N_ + q] < R2_;
            pri[q] = pos ? INFINITY : jax_uniform_r(b * N_ + q);
            if (pos) lp++;
        }
        atomicAdd(&s_npos, lp);
        __syncthreads();

        int n = tile * 16 + n_local;
        float ra = pri[n];

        int cnt = 0;
        const float4* p4 = reinterpret_cast<const float4*>(pri);
        for (int o = 0; o < 8; ++o) {
            float4 v[4];
#pragma unroll
            for (int k = 0; k < 4; ++k) v[k] = p4[part + (o * 4 + k) * 16];
#pragma unroll
            for (int k = 0; k < 4; ++k) {
                int qb = (part + (o * 4 + k) * 16) * 4;
                cnt += ((v[k].x < ra) || (v[k].x == ra && (qb + 0) < n)) ? 1 : 0;
                cnt += ((v[k].y < ra) || (v[k].y == ra && (qb + 1) < n)) ? 1 : 0;
                cnt += ((v[k].z < ra) || (v[k].z == ra && (qb + 2) < n)) ? 1 : 0;
                cnt += ((v[k].w < ra) || (v[k].w == ra && (qb + 3) < n)) ? 1 : 0;
            }
        }
        cnt_sh[part * 17 + n_local] = cnt;
        __syncthreads();

        if (tid < 16) {
            int tot = 0;
#pragma unroll
            for (int p = 0; p < 16; ++p) tot += cnt_sh[p * 17 + tid];
            int npos = s_npos;
            int kk = (npos > 0) ? npos : 2;
            int n2 = tile * 16 + tid;
            float r2 = pri[n2];
            selws[b * N_ + n2] = (r2 == INFINITY) ? 1.0f : ((tot < kk) ? 1.0f : 0.0f);
        }
    }
}

// ---------------------------------------------------------------------------
// K3: per-batch sums (R13-measured; mw read combines 2 j-halves).
// Grid = B*8 = 32 blocks, 1 n per thread. Fixed-order partials + combine.
__global__ __launch_bounds__(256) void finalize_kernel(
        const float* __restrict__ scores, const float* __restrict__ gwh,
        const float* __restrict__ pcw, const int* __restrict__ idxw,
        const float* __restrict__ d2w, const float* __restrict__ mw2,
        const float* __restrict__ selws,
        float* __restrict__ partials, int* __restrict__ counters,
        float* __restrict__ out) {
    int fid = blockIdx.x;                  // 0..31
    int b = fid >> 3;
    int part = fid & 7;
    int tid = threadIdx.x;
    int n = part * 256 + tid;
    __shared__ float wsum[4][5];

    float sc = scores[b * N_ + n];
    float pcl = fminf(fmaxf(sc, EPS_), 0.9999999f);
    bool pos = d2w[b * N_ + n] < R2_;
    float s = pos ? 1.0f : 0.0f;
    float bce = -(s * logf(pcl) + (1.0f - s) * logf(1.0f - pcl));
    float selv = selws[b * N_ + n];
    float sum_sel = selv;
    float sum_bce = bce * selv;
    float sum_pos = s;
    float sum_wl = 0.0f, sum_adds = 0.0f;
    if (pos) {
        int jx = idxw[b * N_ + n];
        float w = pcw[b * M_ + jx];
        float acc = 0.0f;
#pragma unroll
        for (int jb = 0; jb < 10; ++jb) {
            float x = gwh[((size_t)b * 10 + jb) * N_ + n];
            float mh = (w >= c_LO[jb] && w < c_HI[jb]) ? 1.0f : 0.0f;
            float bw = fmaxf(x, 0.0f) - x * mh + log1pf(expf(-fabsf(x)));
            acc += c_BW[jb] * bw;
        }
        sum_wl = acc * 0.1f;
        float mv = fminf(mw2[(size_t)(b * N_ + n) * 2 + 0],
                         mw2[(size_t)(b * N_ + n) * 2 + 1]);
        sum_adds = sc * sqrtf(fmaxf(mv, 0.0f) + 1e-12f);
    }

    // deterministic reduce: wave shuffle + per-wave LDS + thread-0 combine
    float v0 = sum_sel, v1 = sum_bce, v2 = sum_wl, v3 = sum_adds, v4 = sum_pos;
#pragma unroll
    for (int off = 32; off > 0; off >>= 1) {
        v0 += __shfl_down(v0, off);
        v1 += __shfl_down(v1, off);
        v2 += __shfl_down(v2, off);
        v3 += __shfl_down(v3, off);
        v4 += __shfl_down(v4, off);
    }
    int wv = tid >> 6, lane = tid & 63;
    if (lane == 0) {
        wsum[wv][0] = v0; wsum[wv][1] = v1; wsum[wv][2] = v2;
        wsum[wv][3] = v3; wsum[wv][4] = v4;
    }
    __syncthreads();
    if (tid == 0) {
        float t0 = 0, t1 = 0, t2 = 0, t3 = 0, t4 = 0;
#pragma unroll
        for (int w = 0; w < 4; ++w) {
            t0 += wsum[w][0]; t1 += wsum[w][1]; t2 += wsum[w][2];
            t3 += wsum[w][3]; t4 += wsum[w][4];
        }
        float* pp = partials + (size_t)fid * 5;
        pp[0] = t0; pp[1] = t1; pp[2] = t2; pp[3] = t3; pp[4] = t4;
        __threadfence();
        int old = atomicAdd(&counters[1], 1);
        if (old == 32 - 1) {
            __threadfence();
            float bin = 0, wid = 0, ad = 0;
#pragma unroll
            for (int b2 = 0; b2 < B_; ++b2) {
                float u0 = 0, u1 = 0, u2 = 0, u3 = 0, u4 = 0;
#pragma unroll
                for (int p2 = 0; p2 < 8; ++p2) {       // fixed order: deterministic
                    const float* q = partials + (size_t)(b2 * 8 + p2) * 5;
                    u0 += q[0]; u1 += q[1]; u2 += q[2]; u3 += q[3]; u4 += q[4];
                }
                float piv = fmaxf(u4, 1.0f);           // pos_in_view
                bin += u1 / fmaxf(u0, 1.0f);
                wid += u2 / piv;
                ad  += u3 / piv;
            }
            bin *= 0.25f; wid *= 0.25f; ad *= 0.25f;
            out[0] = bin + wid + 3.0f * ad;
            out[1] = bin;
            out[2] = wid;
            out[3] = ad;
        }
    }
}

// ---------------------------------------------------------------------------
extern "C" void kernel_launch(void* const* d_in, const int* in_sizes, int n_in,
                              void* d_out, int out_size, void* d_ws, size_t ws_size,
                              hipStream_t stream) {
    const float* pred_grasps = (const float*)d_in[0];   // (4,2048,4,4)
    const float* pred_scores = (const float*)d_in[1];   // (4,2048,1)
    const float* pred_points = (const float*)d_in[2];   // (4,2048,3)
    const float* gwh         = (const float*)d_in[3];   // (4,10,2048)
    const float* pcp         = (const float*)d_in[4];   // (4,4096,3)
    const float* pcw         = (const float*)d_in[5];   // (4,4096)
    const float* pcr         = (const float*)d_in[6];   // (4,4096,3,3)
    const float* pct         = (const float*)d_in[7];   // (4,4096,3)
    const float* cp          = (const float*)d_in[8];   // (1,5,3)
    const float* cps         = (const float*)d_in[9];   // (1,5,3)
    (void)in_sizes; (void)n_in; (void)out_size; (void)ws_size;

    float* ws = (float*)d_ws;
    int*   idxw  = (int*)ws;                            //   8192
    float* d2w   = ws + 8192;                           //   8192
    float* Pw    = ws + 16384;                          // 131072
    float* Gt    = Pw + 131072;                         // 262144 (quad-SoA)
    float* mw2   = Gt + 262144;                         //  16384 (2 j-halves)
    float* selws = mw2 + 16384;                         //   8192
    float* parts = selws + 8192;                        //    160
    int*   ctrs  = (int*)(parts + 160);                 //      2
    float* outp  = (float*)d_out;

    hipLaunchKernelGGL(nn_prep_kernel, dim3(B_ * (N_ / 8)), dim3(256), 0, stream,
                       pred_points, pcp, pred_grasps, pcr, pct, cp, cps,
                       idxw, d2w, Pw, Gt, ctrs);
    hipLaunchKernelGGL(work_kernel, dim3(ADDS_BLOCKS + RANK_BLOCKS), dim3(256), 0, stream,
                       Pw, (const float4*)Gt, mw2, d2w, selws);
    hipLaunchKernelGGL(finalize_kernel, dim3(B_ * 8), dim3(256), 0, stream,
                       pred_scores, gwh, pcw, idxw, d2w, mw2, selws, parts, ctrs, outp);
}

// Round 15
// 132.228 us; speedup vs baseline: 1.3323x; 1.0661x over previous
//
#include <hip/hip_runtime.h>
#include <math.h>

#define B_ 4
#define N_ 2048
#define M_ 4096

#define ADDS_BLOCKS (B_ * (N_ / 16) * 2)   // 1024 (j-split x2)
#define RANK_BLOCKS (B_ * (N_ / 16))       // 512

// ---- constants (fp32 copies of the reference's) ----
__constant__ float c_LO[10] = {0.0f, 0.00794435329f, 0.0158887021f, 0.0238330509f,
                               0.0317773996f, 0.0397217484f, 0.0476660972f,
                               0.0556104459f, 0.0635547947f, 0.0714991435f};
__constant__ float c_HI[10] = {0.00794435329f, 0.0158887021f, 0.0238330509f,
                               0.0317773996f, 0.0397217484f, 0.0476660972f,
                               0.0556104459f, 0.0635547947f, 0.0714991435f, 0.08f};
__constant__ float c_BW[10] = {0.16652107f, 0.21488856f, 0.37031708f, 0.55618503f,
                               0.75124664f, 0.93943357f, 1.07824539f, 1.19423112f,
                               1.55731375f, 2.34173634f};

#define R2_ 2.5e-05f   // fp32(0.005**2) — matches JAX weak-type cast
#define FAR_ 100000.0f
#define EPS_ 1e-07f

// ---------------------------------------------------------------------------
// JAX threefry2x32, key = jax.random.key(42) -> (0, 42)
__device__ inline unsigned rotl32(unsigned x, int d) { return (x << d) | (x >> (32 - d)); }

__device__ inline void threefry2x32_42(unsigned x0, unsigned x1, unsigned& o0, unsigned& o1) {
    const unsigned k0 = 0u, k1 = 42u;
    const unsigned k2 = k0 ^ k1 ^ 0x1BD11BDAu;
    const unsigned ks[3] = {k0, k1, k2};
    const int rot[2][4] = {{13, 15, 26, 6}, {17, 29, 16, 24}};
    unsigned v0 = x0 + k0;
    unsigned v1 = x1 + k1;
#pragma unroll
    for (int i = 0; i < 5; ++i) {
        const int* r = rot[i & 1];
#pragma unroll
        for (int j = 0; j < 4; ++j) {
            v0 += v1;
            v1 = rotl32(v1, r[j]);
            v1 ^= v0;
        }
        v0 += ks[(i + 1) % 3];
        v1 += ks[(i + 2) % 3] + (unsigned)(i + 1);
    }
    o0 = v0; o1 = v1;
}

__device__ inline float bits_to_uniform(unsigned bits) {
    float f = __uint_as_float((bits >> 9) | 0x3f800000u) - 1.0f;
    return fmaxf(0.0f, f);
}

__device__ inline float jax_uniform_r(int flat) {
    unsigned o0, o1;
    if (flat < 4096) {
        threefry2x32_42((unsigned)flat, (unsigned)(flat + 4096), o0, o1);
        return bits_to_uniform(o0);
    } else {
        threefry2x32_42((unsigned)(flat - 4096), (unsigned)flat, o0, o1);
        return bits_to_uniform(o1);
    }
}

// ---------------------------------------------------------------------------
// K1: fused NN + prep. Grid = B*(N/8) = 1024 blocks.
// Main loop = R14 verbatim. Tail restructured: tree-reduced argmin (16 serial
// steps vs 128) + cooperative rot/trans staging (1 parallel load round vs 12
// dependent rounds). Winner selection is exact lexicographic (d, j) min —
// bit-identical to the serial scan.
__global__ __launch_bounds__(256, 4) void nn_prep_kernel(
        const float* __restrict__ ppts, const float* __restrict__ pcp,
        const float* __restrict__ pred_grasps,
        const float* __restrict__ rot, const float* __restrict__ trans,
        const float* __restrict__ cp, const float* __restrict__ cps,
        int* __restrict__ idx_out, float* __restrict__ d2_out,
        float* __restrict__ Pout, float* __restrict__ Gt,
        int* __restrict__ counters) {
    if (blockIdx.x == 0 && threadIdx.x == 0) { counters[0] = 0; counters[1] = 0; }
    int blk = blockIdx.x;
    int b = blk / (N_ / 8);
    int tile = blk % (N_ / 8);
    int tid = threadIdx.x;
    int ig = tid & 1;             // i-group: 4 consecutive i's
    int part = tid >> 1;          // 0..127
    int i0 = tile * 8 + ig * 4;

    float ax[4], ay[4], az[4], an[4];
#pragma unroll
    for (int ii = 0; ii < 4; ++ii) {
        const float* pp = ppts + ((size_t)b * N_ + i0 + ii) * 3;
        ax[ii] = pp[0]; ay[ii] = pp[1]; az[ii] = pp[2];
        an[ii] = ax[ii] * ax[ii] + ay[ii] * ay[ii] + az[ii] * az[ii];
    }

    const float4* pb4 = reinterpret_cast<const float4*>(pcp + (size_t)b * M_ * 3);
    float best[4] = {INFINITY, INFINITY, INFINITY, INFINITY};
    int bidx[4] = {0, 0, 0, 0};
    for (int g = 0; g < 8; ++g) {
        int grp = g * 128 + part;            // group of 4 contact points
        float4 q0 = pb4[grp * 3 + 0];
        float4 q1 = pb4[grp * 3 + 1];
        float4 q2 = pb4[grp * 3 + 2];
        float px[4] = {q0.x, q0.w, q1.z, q2.y};
        float py[4] = {q0.y, q1.x, q1.w, q2.z};
        float pz[4] = {q0.z, q1.y, q2.x, q2.w};
#pragma unroll
        for (int k = 0; k < 4; ++k) {
            float bn = px[k] * px[k] + py[k] * py[k] + pz[k] * pz[k];
            int j = grp * 4 + k;             // ascending within thread
#pragma unroll
            for (int ii = 0; ii < 4; ++ii) {
                float cross = ax[ii] * px[k] + ay[ii] * py[k] + az[ii] * pz[k];
                float d = an[ii] + bn - 2.0f * cross;
                d = fmaxf(d, 0.0f);
                if (d < best[ii]) { best[ii] = d; bidx[ii] = j; }  // first occurrence
            }
        }
    }

    __shared__ float sd[8][128];
    __shared__ int si[8][128];
    __shared__ int win_bi[8];
    __shared__ float win_bb[8];
    __shared__ float rt[8][12];
#pragma unroll
    for (int ii = 0; ii < 4; ++ii) {
        sd[ig * 4 + ii][part] = best[ii];
        si[ig * 4 + ii][part] = bidx[ii];
    }
    __syncthreads();

    // ---- tree-reduced lexicographic (d, j) argmin ----
    // stage 1: 128 -> 32 per i (8 i x 32 threads, 4 compares each)
    {
        int i2 = tid >> 5, r = tid & 31;
        float bb = sd[i2][r * 4];
        int bi = si[i2][r * 4];
#pragma unroll
        for (int p = 1; p < 4; ++p) {
            float dv = sd[i2][r * 4 + p];
            int iv = si[i2][r * 4 + p];
            if (dv < bb || (dv == bb && iv < bi)) { bb = dv; bi = iv; }
        }
        __syncthreads();
        sd[i2][r] = bb; si[i2][r] = bi;
    }
    __syncthreads();
    // stage 2: 32 -> 8 per i (8 i x 8 threads)
    if (tid < 64) {
        int i2 = tid >> 3, r = tid & 7;
        float bb = sd[i2][r * 4];
        int bi = si[i2][r * 4];
#pragma unroll
        for (int p = 1; p < 4; ++p) {
            float dv = sd[i2][r * 4 + p];
            int iv = si[i2][r * 4 + p];
            if (dv < bb || (dv == bb && iv < bi)) { bb = dv; bi = iv; }
        }
        __syncthreads();
        sd[i2][r] = bb; si[i2][r] = bi;
    } else {
        __syncthreads();
    }
    __syncthreads();
    // stage 3: 8 -> 1 per i (8 threads, 8 compares)
    if (tid < 8) {
        float bb = sd[tid][0];
        int bi = si[tid][0];
#pragma unroll
        for (int p = 1; p < 8; ++p) {
            float dv = sd[tid][p];
            int iv = si[tid][p];
            if (dv < bb || (dv == bb && iv < bi)) { bb = dv; bi = iv; }
        }
        int n = tile * 8 + tid;
        idx_out[b * N_ + n] = bi;
        d2_out[b * N_ + n] = bb;
        win_bi[tid] = bi;
        win_bb[tid] = bb;
    }
    __syncthreads();

    // ---- cooperative rot/trans staging: 8 n x 12 comps in one round ----
    if (tid < 96) {
        int n2 = tid / 12, c = tid % 12;
        int bi2 = win_bi[n2];
        bool succ2 = win_bb[n2] < R2_;
        float v;
        if (succ2) {
            v = (c < 9) ? rot[((size_t)b * M_ + bi2) * 9 + c]
                        : trans[((size_t)b * M_ + bi2) * 3 + (c - 9)];
        } else {
            v = FAR_;
        }
        rt[n2][c] = v;
    }
    __syncthreads();

    if (tid < 8) {
        int n = tile * 8 + tid;
        size_t i = (size_t)b * N_ + n;
        const float* g = pred_grasps + i * 16;
        float R[3][3] = {{g[0], g[1], g[2]}, {g[4], g[5], g[6]}, {g[8], g[9], g[10]}};
        float t[3] = {g[3], g[7], g[11]};

        float* P = Pout + i * 16;
        float pn = 0.0f;
#pragma unroll
        for (int c = 0; c < 5; ++c) {
            float cx = cp[c * 3], cy = cp[c * 3 + 1], cz = cp[c * 3 + 2];
#pragma unroll
            for (int kk = 0; kk < 3; ++kk) {
                float v = R[kk][0] * cx + R[kk][1] * cy + R[kk][2] * cz + t[kk];
                P[c * 3 + kk] = v;
                pn += v * v;
            }
        }
        P[15] = pn;

        float RL[3][3] = {{rt[tid][0], rt[tid][1], rt[tid][2]},
                          {rt[tid][3], rt[tid][4], rt[tid][5]},
                          {rt[tid][6], rt[tid][7], rt[tid][8]}};
        float TL[3] = {rt[tid][9], rt[tid][10], rt[tid][11]};

        // quad-SoA G write: comp c -> gtb[(c/4)*N_*4 + (c%4)]
        float* gtb = Gt + ((size_t)b * 8 * N_ + n) * 4;
        float gn = 0.0f, gsn = 0.0f;
#pragma unroll
        for (int c = 0; c < 5; ++c) {
            float cx = cp[c * 3], cy = cp[c * 3 + 1], cz = cp[c * 3 + 2];
#pragma unroll
            for (int kk = 0; kk < 3; ++kk) {
                int comp = c * 3 + kk;
                float v = RL[kk][0] * cx + RL[kk][1] * cy + RL[kk][2] * cz + TL[kk];
                gtb[(size_t)(comp >> 2) * (N_ * 4) + (comp & 3)] = v;
                gn += v * v;
            }
        }
        gtb[(size_t)(15 >> 2) * (N_ * 4) + (15 & 3)] = gn;
#pragma unroll
        for (int c = 0; c < 5; ++c) {
            float cx = cps[c * 3], cy = cps[c * 3 + 1], cz = cps[c * 3 + 2];
#pragma unroll
            for (int kk = 0; kk < 3; ++kk) {
                int comp = 16 + c * 3 + kk;
                float v = RL[kk][0] * cx + RL[kk][1] * cy + RL[kk][2] * cz + TL[kk];
                gtb[(size_t)(comp >> 2) * (N_ * 4) + (comp & 3)] = v;
                gsn += v * v;
            }
        }
        gtb[(size_t)(31 >> 2) * (N_ * 4) + (31 & 3)] = gsn;
    }
}

// ---------------------------------------------------------------------------
// K2: merged adds + rank (R14 verbatim).
//   [0, 1024):    ADD-S min, quad-SoA G, 4 i/wave, j-split (R13-measured)
//   [1024, 1536): hard-negative selection (R6-measured)
__global__ __launch_bounds__(256, 4) void work_kernel(
        const float* __restrict__ Parr, const float4* __restrict__ Gt4,
        float* __restrict__ mOut2,
        const float* __restrict__ d2w, float* __restrict__ selws) {
    __shared__ __align__(16) char smem[9600];
    int bid = blockIdx.x;
    int tid = threadIdx.x;

    if (bid < ADDS_BLOCKS) {
        // ================= adds role =================
        int b = bid / (2 * (N_ / 16));
        int rem = bid % (2 * (N_ / 16));
        int tile = rem >> 1;
        int jh = rem & 1;                      // j-half
        int w = tid >> 6;                      // wave 0..3
        int lane = tid & 63;
        int i0 = tile * 16 + w * 4;

        const float4* P4 = reinterpret_cast<const float4*>(Parr) +
                           ((size_t)b * N_ + i0) * 4;
        float Pv[4][16];
#pragma unroll
        for (int h = 0; h < 4; ++h)
#pragma unroll
            for (int q = 0; q < 4; ++q) {
                float4 v = P4[h * 4 + q];
                Pv[h][q * 4 + 0] = v.x; Pv[h][q * 4 + 1] = v.y;
                Pv[h][q * 4 + 2] = v.z; Pv[h][q * 4 + 3] = v.w;
            }

        const float4* gq = Gt4 + (size_t)b * 8 * N_;
        float best[4] = {INFINITY, INFINITY, INFINITY, INFINITY};
        int jb0 = jh * (N_ / 128);             // 16 iterations per half
        for (int jb = jb0; jb < jb0 + (N_ / 128); ++jb) {
            int j = jb * 64 + lane;
            float g[16];
            // half 1: quads 0..3 = comps 0..15 (G + norm)
            {
                float4 h0 = gq[(size_t)0 * N_ + j];
                float4 h1 = gq[(size_t)1 * N_ + j];
                float4 h2 = gq[(size_t)2 * N_ + j];
                float4 h3 = gq[(size_t)3 * N_ + j];
                g[0] = h0.x; g[1] = h0.y; g[2] = h0.z; g[3] = h0.w;
                g[4] = h1.x; g[5] = h1.y; g[6] = h1.z; g[7] = h1.w;
                g[8] = h2.x; g[9] = h2.y; g[10] = h2.z; g[11] = h2.w;
                g[12] = h3.x; g[13] = h3.y; g[14] = h3.z; g[15] = h3.w;
            }
            float s1[4];
            {
                float d[4] = {0.0f, 0.0f, 0.0f, 0.0f};
#pragma unroll
                for (int q = 0; q < 15; ++q)
#pragma unroll
                    for (int ii = 0; ii < 4; ++ii) d[ii] += Pv[ii][q] * g[q];
#pragma unroll
                for (int ii = 0; ii < 4; ++ii) s1[ii] = Pv[ii][15] + g[15] - 2.0f * d[ii];
            }
            // half 2: quads 4..7 = comps 16..31 (Gs + norm)
            {
                float4 h0 = gq[(size_t)4 * N_ + j];
                float4 h1 = gq[(size_t)5 * N_ + j];
                float4 h2 = gq[(size_t)6 * N_ + j];
                float4 h3 = gq[(size_t)7 * N_ + j];
                g[0] = h0.x; g[1] = h0.y; g[2] = h0.z; g[3] = h0.w;
                g[4] = h1.x; g[5] = h1.y; g[6] = h1.z; g[7] = h1.w;
                g[8] = h2.x; g[9] = h2.y; g[10] = h2.z; g[11] = h2.w;
                g[12] = h3.x; g[13] = h3.y; g[14] = h3.z; g[15] = h3.w;
            }
            {
                float d[4] = {0.0f, 0.0f, 0.0f, 0.0f};
#pragma unroll
                for (int q = 0; q < 15; ++q)
#pragma unroll
                    for (int ii = 0; ii < 4; ++ii) d[ii] += Pv[ii][q] * g[q];
#pragma unroll
                for (int ii = 0; ii < 4; ++ii) {
                    float s2 = Pv[ii][15] + g[15] - 2.0f * d[ii];
                    best[ii] = fminf(best[ii], fminf(s1[ii], s2));
                }
            }
        }
        // 64-lane min butterfly
#pragma unroll
        for (int m = 32; m > 0; m >>= 1) {
#pragma unroll
            for (int ii = 0; ii < 4; ++ii)
                best[ii] = fminf(best[ii], __shfl_xor(best[ii], m));
        }
        if (lane == 0) {
#pragma unroll
            for (int ii = 0; ii < 4; ++ii)
                mOut2[(size_t)(b * N_ + i0 + ii) * 2 + jh] = best[ii];
        }
    } else {
        // ================= rank role =================
        int rid = bid - ADDS_BLOCKS;
        int b = rid / (N_ / 16);
        int tile = rid % (N_ / 16);
        int n_local = tid & 15;
        int part = tid >> 4;               // 0..15

        float* pri = (float*)smem;                   // [2048] floats
        int* cnt_sh = (int*)(smem + 8192);           // [16][17]
        __shared__ int s_npos;
        if (tid == 0) s_npos = 0;
        __syncthreads();

        int lp = 0;
        for (int q = tid; q < N_; q += 256) {
            bool pos = d2w[b * N_ + q] < R2_;
            pri[q] = pos ? INFINITY : jax_uniform_r(b * N_ + q);
            if (pos) lp++;
        }
        atomicAdd(&s_npos, lp);
        __syncthreads();

        int n = tile * 16 + n_local;
        float ra = pri[n];

        int cnt = 0;
        const float4* p4 = reinterpret_cast<const float4*>(pri);
        for (int o = 0; o < 8; ++o) {
            float4 v[4];
#pragma unroll
            for (int k = 0; k < 4; ++k) v[k] = p4[part + (o * 4 + k) * 16];
#pragma unroll
            for (int k = 0; k < 4; ++k) {
                int qb = (part + (o * 4 + k) * 16) * 4;
                cnt += ((v[k].x < ra) || (v[k].x == ra && (qb + 0) < n)) ? 1 : 0;
                cnt += ((v[k].y < ra) || (v[k].y == ra && (qb + 1) < n)) ? 1 : 0;
                cnt += ((v[k].z < ra) || (v[k].z == ra && (qb + 2) < n)) ? 1 : 0;
                cnt += ((v[k].w < ra) || (v[k].w == ra && (qb + 3) < n)) ? 1 : 0;
            }
        }
        cnt_sh[part * 17 + n_local] = cnt;
        __syncthreads();

        if (tid < 16) {
            int tot = 0;
#pragma unroll
            for (int p = 0; p < 16; ++p) tot += cnt_sh[p * 17 + tid];
            int npos = s_npos;
            int kk = (npos > 0) ? npos : 2;
            int n2 = tile * 16 + tid;
            float r2 = pri[n2];
            selws[b * N_ + n2] = (r2 == INFINITY) ? 1.0f : ((tot < kk) ? 1.0f : 0.0f);
        }
    }
}

// ---------------------------------------------------------------------------
// K3: per-batch sums (R14 verbatim). Grid = B*8 = 32 blocks, 1 n per thread.
__global__ __launch_bounds__(256) void finalize_kernel(
        const float* __restrict__ scores, const float* __restrict__ gwh,
        const float* __restrict__ pcw, const int* __restrict__ idxw,
        const float* __restrict__ d2w, const float* __restrict__ mw2,
        const float* __restrict__ selws,
        float* __restrict__ partials, int* __restrict__ counters,
        float* __restrict__ out) {
    int fid = blockIdx.x;                  // 0..31
    int b = fid >> 3;
    int part = fid & 7;
    int tid = threadIdx.x;
    int n = part * 256 + tid;
    __shared__ float wsum[4][5];

    float sc = scores[b * N_ + n];
    float pcl = fminf(fmaxf(sc, EPS_), 0.9999999f);
    bool pos = d2w[b * N_ + n] < R2_;
    float s = pos ? 1.0f : 0.0f;
    float bce = -(s * logf(pcl) + (1.0f - s) * logf(1.0f - pcl));
    float selv = selws[b * N_ + n];
    float sum_sel = selv;
    float sum_bce = bce * selv;
    float sum_pos = s;
    float sum_wl = 0.0f, sum_adds = 0.0f;
    if (pos) {
        int jx = idxw[b * N_ + n];
        float w = pcw[b * M_ + jx];
        float acc = 0.0f;
#pragma unroll
        for (int jb = 0; jb < 10; ++jb) {
            float x = gwh[((size_t)b * 10 + jb) * N_ + n];
            float mh = (w >= c_LO[jb] && w < c_HI[jb]) ? 1.0f : 0.0f;
            float bw = fmaxf(x, 0.0f) - x * mh + log1pf(expf(-fabsf(x)));
            acc += c_BW[jb] * bw;
        }
        sum_wl = acc * 0.1f;
        float mv = fminf(mw2[(size_t)(b * N_ + n) * 2 + 0],
                         mw2[(size_t)(b * N_ + n) * 2 + 1]);
        sum_adds = sc * sqrtf(fmaxf(mv, 0.0f) + 1e-12f);
    }

    // deterministic reduce: wave shuffle + per-wave LDS + thread-0 combine
    float v0 = sum_sel, v1 = sum_bce, v2 = sum_wl, v3 = sum_adds, v4 = sum_pos;
#pragma unroll
    for (int off = 32; off > 0; off >>= 1) {
        v0 += __shfl_down(v0, off);
        v1 += __shfl_down(v1, off);
        v2 += __shfl_down(v2, off);
        v3 += __shfl_down(v3, off);
        v4 += __shfl_down(v4, off);
    }
    int wv = tid >> 6, lane = tid & 63;
    if (lane == 0) {
        wsum[wv][0] = v0; wsum[wv][1] = v1; wsum[wv][2] = v2;
        wsum[wv][3] = v3; wsum[wv][4] = v4;
    }
    __syncthreads();
    if (tid == 0) {
        float t0 = 0, t1 = 0, t2 = 0, t3 = 0, t4 = 0;
#pragma unroll
        for (int w = 0; w < 4; ++w) {
            t0 += wsum[w][0]; t1 += wsum[w][1]; t2 += wsum[w][2];
            t3 += wsum[w][3]; t4 += wsum[w][4];
        }
        float* pp = partials + (size_t)fid * 5;
        pp[0] = t0; pp[1] = t1; pp[2] = t2; pp[3] = t3; pp[4] = t4;
        __threadfence();
        int old = atomicAdd(&counters[1], 1);
        if (old == 32 - 1) {
            __threadfence();
            float bin = 0, wid = 0, ad = 0;
#pragma unroll
            for (int b2 = 0; b2 < B_; ++b2) {
                float u0 = 0, u1 = 0, u2 = 0, u3 = 0, u4 = 0;
#pragma unroll
                for (int p2 = 0; p2 < 8; ++p2) {       // fixed order: deterministic
                    const float* q = partials + (size_t)(b2 * 8 + p2) * 5;
                    u0 += q[0]; u1 += q[1]; u2 += q[2]; u3 += q[3]; u4 += q[4];
                }
                float piv = fmaxf(u4, 1.0f);           // pos_in_view
                bin += u1 / fmaxf(u0, 1.0f);
                wid += u2 / piv;
                ad  += u3 / piv;
            }
            bin *= 0.25f; wid *= 0.25f; ad *= 0.25f;
            out[0] = bin + wid + 3.0f * ad;
            out[1] = bin;
            out[2] = wid;
            out[3] = ad;
        }
    }
}

// ---------------------------------------------------------------------------
extern "C" void kernel_launch(void* const* d_in, const int* in_sizes, int n_in,
                              void* d_out, int out_size, void* d_ws, size_t ws_size,
                              hipStream_t stream) {
    const float* pred_grasps = (const float*)d_in[0];   // (4,2048,4,4)
    const float* pred_scores = (const float*)d_in[1];   // (4,2048,1)
    const float* pred_points = (const float*)d_in[2];   // (4,2048,3)
    const float* gwh         = (const float*)d_in[3];   // (4,10,2048)
    const float* pcp         = (const float*)d_in[4];   // (4,4096,3)
    const float* pcw         = (const float*)d_in[5];   // (4,4096)
    const float* pcr         = (const float*)d_in[6];   // (4,4096,3,3)
    const float* pct         = (const float*)d_in[7];   // (4,4096,3)
    const float* cp          = (const float*)d_in[8];   // (1,5,3)
    const float* cps         = (const float*)d_in[9];   // (1,5,3)
    (void)in_sizes; (void)n_in; (void)out_size; (void)ws_size;

    float* ws = (float*)d_ws;
    int*   idxw  = (int*)ws;                            //   8192
    float* d2w   = ws + 8192;                           //   8192
    float* Pw    = ws + 16384;                          // 131072
    float* Gt    = Pw + 131072;                         // 262144 (quad-SoA)
    float* mw2   = Gt + 262144;                         //  16384 (2 j-halves)
    float* selws = mw2 + 16384;                         //   8192
    float* parts = selws + 8192;                        //    160
    int*   ctrs  = (int*)(parts + 160);                 //      2
    float* outp  = (float*)d_out;

    hipLaunchKernelGGL(nn_prep_kernel, dim3(B_ * (N_ / 8)), dim3(256), 0, stream,
                       pred_points, pcp, pred_grasps, pcr, pct, cp, cps,
                       idxw, d2w, Pw, Gt, ctrs);
    hipLaunchKernelGGL(work_kernel, dim3(ADDS_BLOCKS + RANK_BLOCKS), dim3(256), 0, stream,
                       Pw, (const float4*)Gt, mw2, d2w, selws);
    hipLaunchKernelGGL(finalize_kernel, dim3(B_ * 8), dim3(256), 0, stream,
                       pred_scores, gwh, pcw, idxw, d2w, mw2, selws, parts, ctrs, outp);
}